// Round 6
// baseline (728.796 us; speedup 1.0000x reference)
//
#include <hip/hip_runtime.h>
#include <hip/hip_bf16.h>
#include <math.h>

#define NNODES 100000
#define NEDGES 500000
#define NB_SCAN 391  // ceil(NNODES/256)

typedef __attribute__((ext_vector_type(8))) short short8;
typedef __attribute__((ext_vector_type(4))) float f32x4;

__device__ __forceinline__ float bf2f(__hip_bfloat16 v) {
  return __bfloat162float(v);
}
__device__ __forceinline__ unsigned short f2b(float f) {
  __hip_bfloat16 h = __float2bfloat16(f);
  return *(unsigned short*)&h;
}
__device__ __forceinline__ float bits2f_lo(unsigned u) {
  return __uint_as_float(u << 16);
}
__device__ __forceinline__ float bits2f_hi(unsigned u) {
  return __uint_as_float(u & 0xffff0000u);
}
// packed slot record: x = drug | (n&0x7FFF)<<17 ; y = other | (n>>15)<<17 | role<<19
__device__ __forceinline__ int dec_n(int2 r) {
  return (int)(((unsigned)r.x >> 17) | ((((unsigned)r.y >> 17) & 3u) << 15));
}

// ========== Fused weight-prep (blocks 0..211) + degree count (rest) ===========
__global__ void k_prepdeg(const float* __restrict__ W0, const float* __restrict__ a10,
                          const float* __restrict__ a20, const float* __restrict__ a30,
                          const float* __restrict__ W1, const float* __restrict__ Wsk,
                          const float* __restrict__ a11, const float* __restrict__ a21,
                          const float* __restrict__ a31,
                          __hip_bfloat16* __restrict__ B0,
                          __hip_bfloat16* __restrict__ B1,
                          const int* __restrict__ ei, int* __restrict__ deg) {
  if (blockIdx.x >= 212) {
    const int idx = (blockIdx.x - 212) * 256 + threadIdx.x;
    if (idx < 2 * NEDGES) atomicAdd(&deg[ei[NEDGES + idx]], 1);
    return;
  }
  if (blockIdx.x < 68) {
    const int t = blockIdx.x * 256 + threadIdx.x;  // < 17408
    const int j = t & 7, l = (t >> 3) & 63, s = (t >> 9) & 1, g = t >> 10;
    const int k = s * 32 + ((l >> 4) << 3) + j;
    const int col = g * 16 + (l & 15);
    float v = 0.f;
    if (col < 256) {
      v = W0[col * 64 + k];
    } else if (col < 268) {
      const int idx = col - 256;
      const int r = idx >> 2, h = idx & 3;
      const float* av = (r == 0) ? a10 : (r == 1) ? a20 : a30;
      for (int f = 0; f < 64; ++f)
        v = fmaf(av[h * 64 + f], W0[(h * 64 + f) * 64 + k], v);
    }
    B0[t] = __float2bfloat16(v);
  } else {
    const int t = (blockIdx.x - 68) * 256 + threadIdx.x;  // < 36864
    const int j = t & 7, l = (t >> 3) & 63, s = (t >> 9) & 7, g = t >> 12;
    const int kp = s * 32 + ((l >> 4) << 3) + j;
    const int k = (kp & 3) * 64 + (kp >> 2);  // permuted -> original (head-ilv A)
    const int col = g * 16 + (l & 15);
    float v = 0.f;
    if (col < 64) {
      v = W1[col * 256 + k];
    } else if (col < 128) {
      v = Wsk[(col - 64) * 256 + k];
    } else if (col < 131) {
      const int r = col - 128;
      const float* av = (r == 0) ? a11 : (r == 1) ? a21 : a31;
      for (int f = 0; f < 64; ++f) v = fmaf(av[f], W1[f * 256 + k], v);
    }
    B1[t] = __float2bfloat16(v);
  }
}

// ====== Fused: blocks 0..390 = wave-parallel lookback scan; rest = mm0 ========
#define FLG_AGG (1 << 30)
#define FLG_PRE (2 << 30)
#define VMASK 0x3FFFFFFF
#define LDA0 72
__global__ __launch_bounds__(256) void k_scanmm0(
    const int* __restrict__ deg, int* __restrict__ offs, int* __restrict__ cursor,
    int* __restrict__ desc,  // desc[0]=ticket, desc[1..NB_SCAN]=status
    const float* __restrict__ x, const short* __restrict__ B0,
    __hip_bfloat16* __restrict__ proj0, float* __restrict__ s1,
    float* __restrict__ s2, float* __restrict__ s3) {
  __shared__ __hip_bfloat16 As[64 * LDA0];
  __shared__ int sh[256];
  __shared__ int sbid, sexc;
  const int t = threadIdx.x;

  if (blockIdx.x < NB_SCAN) {
    // ---------------- decoupled-lookback exclusive scan of deg ----------------
    if (t == 0) sbid = atomicAdd(&desc[0], 1);
    __syncthreads();
    const int b = sbid;
    const int i = b * 256 + t;
    const int v = (i < NNODES) ? deg[i] : 0;
    sh[t] = v;
    __syncthreads();
    for (int d = 1; d < 256; d <<= 1) {
      const int add = (t >= d) ? sh[t - d] : 0;
      __syncthreads();
      sh[t] += add;
      __syncthreads();
    }
    const int total = sh[255];
    int* st = desc + 1;
    if (t == 0) {
      __hip_atomic_store(&st[b], total | (b == 0 ? FLG_PRE : FLG_AGG),
                         __ATOMIC_RELEASE, __HIP_MEMORY_SCOPE_AGENT);
      if (b == 0) sexc = 0;
    }
    if (b > 0 && t < 64) {
      // wave 0: read 64 predecessor statuses per step
      int exc = 0;
      int p = b - 1;
      while (true) {
        const int idx = p - t;
        int d;
        if (idx >= 0) {
          d = __hip_atomic_load(&st[idx], __ATOMIC_ACQUIRE,
                                __HIP_MEMORY_SCOPE_AGENT);
        } else {
          d = FLG_PRE;  // synthetic prefix=0 beyond block 0 (never reached)
        }
        const unsigned long long pre = __ballot(d & FLG_PRE);
        const unsigned long long zer = __ballot(d == 0);
        if (pre) {
          const int L = __ffsll(pre) - 1;  // nearest PRE (lowest lane)
          const unsigned long long lowmask =
              (L >= 63) ? ~0ULL : ((1ULL << (L + 1)) - 1);
          if (zer & lowmask) {  // unposted gap before the PRE -> retry
            __builtin_amdgcn_s_sleep(1);
            continue;
          }
          int c = (t <= L) ? (d & VMASK) : 0;
          for (int m = 1; m < 64; m <<= 1) c += __shfl_xor(c, m);
          exc += c;
          break;
        }
        if (zer) {  // any unposted in window -> retry
          __builtin_amdgcn_s_sleep(1);
          continue;
        }
        int c = d & VMASK;  // all 64 are AGG: take the window, walk back
        for (int m = 1; m < 64; m <<= 1) c += __shfl_xor(c, m);
        exc += c;
        p -= 64;
      }
      if (t == 0) {
        __hip_atomic_store(&st[b], (exc + total) | FLG_PRE, __ATOMIC_RELEASE,
                           __HIP_MEMORY_SCOPE_AGENT);
        sexc = exc;
      }
    }
    __syncthreads();
    const int exc = sexc;
    if (i < NNODES) {
      const int o = exc + sh[t] - v;
      offs[i] = o;
      cursor[i] = o;
    }
    if (b == 0 && t == 0) offs[NNODES] = 2 * NEDGES;
    return;
  }

  // ---------------- Layer-0 MFMA GEMM: [N,64] x [64,272] ----------------------
  // proj0 stored HEAD-INTERLEAVED: proj0[n*256 + f*4 + h]; packed uint2 stores.
  const int lane = t & 63, w = t >> 6;
  const int base = (blockIdx.x - NB_SCAN) * 64;
  for (int q = 0; q < 4; ++q) {
    const int i = q * 256 + t;
    const int r = i >> 4;
    const int c4 = i & 15;
    int rg = base + r;
    if (rg >= NNODES) rg = NNODES - 1;
    const float4 v = ((const float4*)(x + (size_t)rg * 64))[c4];
    __hip_bfloat16* dst = &As[r * LDA0 + c4 * 4];
    dst[0] = __float2bfloat16(v.x);
    dst[1] = __float2bfloat16(v.y);
    dst[2] = __float2bfloat16(v.z);
    dst[3] = __float2bfloat16(v.w);
  }
  __syncthreads();
  const short8* B8 = (const short8*)B0;
  f32x4 acc[17];
#pragma unroll
  for (int g = 0; g < 17; ++g) acc[g] = (f32x4){0.f, 0.f, 0.f, 0.f};
  const int aoff = (w * 16 + (lane & 15)) * LDA0 + (lane >> 4) * 8;
#pragma unroll
  for (int s = 0; s < 2; ++s) {
    const short8 af = *(const short8*)(&As[aoff + s * 32]);
#pragma unroll
    for (int g = 0; g < 17; ++g) {
      const short8 bf = B8[(g * 2 + s) * 64 + lane];
      acc[g] = __builtin_amdgcn_mfma_f32_16x16x32_bf16(af, bf, acc[g], 0, 0, 0);
    }
  }
  const int r0 = base + w * 16 + (lane >> 4) * 4;
  const int cn = lane & 15;
  // packed epilogue: heads h of feature f=g*16+cn are acc[g+4h]
#pragma unroll
  for (int g = 0; g < 4; ++g) {
    const int f = g * 16 + cn;
#pragma unroll
    for (int r = 0; r < 4; ++r) {
      const int row = r0 + r;
      if (row < NNODES) {
        uint2 o;
        o.x = (unsigned)f2b(acc[g][r]) | ((unsigned)f2b(acc[g + 4][r]) << 16);
        o.y = (unsigned)f2b(acc[g + 8][r]) | ((unsigned)f2b(acc[g + 12][r]) << 16);
        *(uint2*)(proj0 + (size_t)row * 256 + f * 4) = o;
      }
    }
  }
#pragma unroll
  for (int r = 0; r < 4; ++r) {
    const int row = r0 + r;
    if (row < NNODES) {
      if (cn < 4) s1[row * 4 + cn] = acc[16][r];
      else if (cn < 8) s2[row * 4 + (cn - 4)] = acc[16][r];
      else if (cn < 12) s3[row * 4 + (cn - 8)] = acc[16][r];
    }
  }
}

// Fill packed slot records (no rcvA).
__global__ void k_fill3p(const int* __restrict__ ei, int* __restrict__ cursor,
                         int2* __restrict__ recA) {
  const int idx = blockIdx.x * 256 + threadIdx.x;
  if (idx >= 2 * NEDGES) return;
  const int n = ei[NEDGES + idx];
  const int e = (idx < NEDGES) ? idx : idx - NEDGES;
  const int drug = ei[e];
  const int other = (idx < NEDGES) ? ei[2 * NEDGES + e] : ei[NEDGES + e];
  const int role = (idx < NEDGES) ? 0 : 1;
  const int pos = atomicAdd(&cursor[n], 1);
  const int px = drug | ((n & 0x7FFF) << 17);
  const int py = other | (((n >> 15) & 3) << 17) | (role << 19);
  recA[pos] = make_int2(px, py);
}

// ====== Layer-0 exp-scores + denominator atomics, SLOT-PARALLEL ===============
__global__ void k_esx0s(const int2* __restrict__ recA, const float* __restrict__ s1,
                        const float* __restrict__ s2, const float* __restrict__ s3,
                        float* __restrict__ esx, float* __restrict__ sums) {
  const int j = blockIdx.x * 256 + threadIdx.x;
  if (j >= 2 * NEDGES) return;
  const int2 rec = recA[j];
  const int drug = rec.x & 0x1FFFF;
  const int o = rec.y & 0x1FFFF;
  const int n = dec_n(rec);
  const int role = ((unsigned)rec.y >> 19) & 1;
  const float4 A = ((const float4*)s1)[drug];
  const float4 T = ((const float4*)s2)[role ? o : n];
  const float4 D = ((const float4*)s3)[role ? n : o];
  float4 es;
  float s;
  s = A.x + T.x + D.x; s = s > 0.f ? s : 0.2f * s; es.x = __expf(s);
  s = A.y + T.y + D.y; s = s > 0.f ? s : 0.2f * s; es.y = __expf(s);
  s = A.z + T.z + D.z; s = s > 0.f ? s : 0.2f * s; es.z = __expf(s);
  s = A.w + T.w + D.w; s = s > 0.f ? s : 0.2f * s; es.w = __expf(s);
  ((float4*)esx)[j] = es;
  atomicAdd(&sums[n * 4 + 0], es.x);
  atomicAdd(&sums[n * 4 + 1], es.y);
  atomicAdd(&sums[n * 4 + 2], es.z);
  atomicAdd(&sums[n * 4 + 3], es.w);
}

// ====== Layer-0 aggregate, wave/node, FUSED normalization =====================
// 32 lanes per slot (uint4 = 16B/lane), 2 slots per wave-step; half-combine via
// __shfl_xor(32). att computed on the fly: esx[j]*rcp(sums[n]+sums[o]).
__global__ __launch_bounds__(256) void k_agg0w(
    const int* __restrict__ offs, const int2* __restrict__ recA,
    const float* __restrict__ esx, const float* __restrict__ sums,
    const __hip_bfloat16* __restrict__ proj0, const float* __restrict__ x,
    const float* __restrict__ b0, __hip_bfloat16* __restrict__ out0b) {
  const int lane = threadIdx.x & 63, wid = threadIdx.x >> 6;
  const int n = blockIdx.x * 4 + wid;
  if (n >= NNODES) return;
  const int beg = offs[n], end = offs[n + 1];
  const int h = lane >> 5;   // which slot of the pair
  const int sl = lane & 31;  // features 2*sl, 2*sl+1 (x 4 heads)
  const float4 sn = ((const float4*)sums)[n];
  float a0 = 0.f, a1 = 0.f, a2 = 0.f, a3 = 0.f;
  float a4 = 0.f, a5 = 0.f, a6 = 0.f, a7 = 0.f;

#define PAIR(J, LIVE)                                                          \
  {                                                                            \
    const int jj = (J) + h;                                                    \
    const bool lv = (LIVE);                                                    \
    const int js = lv ? jj : beg;                                              \
    const int2 rec = recA[js];                                                 \
    const int dd = rec.x & 0x1FFFF;                                            \
    const int o = rec.y & 0x1FFFF;                                             \
    const float4 e = ((const float4*)esx)[js];                                 \
    const float4 so = ((const float4*)sums)[o];                                \
    const uint4 r = *(const uint4*)(proj0 + (size_t)dd * 256 + sl * 8);        \
    const float lm = lv ? 1.f : 0.f;                                           \
    const float t0 = lm * e.x * __builtin_amdgcn_rcpf(sn.x + so.x + 1e-16f);   \
    const float t1 = lm * e.y * __builtin_amdgcn_rcpf(sn.y + so.y + 1e-16f);   \
    const float t2 = lm * e.z * __builtin_amdgcn_rcpf(sn.z + so.z + 1e-16f);   \
    const float t3 = lm * e.w * __builtin_amdgcn_rcpf(sn.w + so.w + 1e-16f);   \
    a0 = fmaf(bits2f_lo(r.x), t0, a0);                                         \
    a1 = fmaf(bits2f_hi(r.x), t1, a1);                                         \
    a2 = fmaf(bits2f_lo(r.y), t2, a2);                                         \
    a3 = fmaf(bits2f_hi(r.y), t3, a3);                                         \
    a4 = fmaf(bits2f_lo(r.z), t0, a4);                                         \
    a5 = fmaf(bits2f_hi(r.z), t1, a5);                                         \
    a6 = fmaf(bits2f_lo(r.w), t2, a6);                                         \
    a7 = fmaf(bits2f_hi(r.w), t3, a7);                                         \
  }

  int j = beg;
  for (; j + 4 <= end; j += 4) {
    PAIR(j, true)
    PAIR(j + 2, true)
  }
  for (; j < end; j += 2) PAIR(j, jj < end)
#undef PAIR

  // combine the two slot-halves
  a0 += __shfl_xor(a0, 32); a1 += __shfl_xor(a1, 32);
  a2 += __shfl_xor(a2, 32); a3 += __shfl_xor(a3, 32);
  a4 += __shfl_xor(a4, 32); a5 += __shfl_xor(a5, 32);
  a6 += __shfl_xor(a6, 32); a7 += __shfl_xor(a7, 32);

  if (h == 0) {
    const float2 xs = ((const float2*)(x + (size_t)n * 64))[sl];
    const int f0 = sl * 2;
    float v0 = a0 + xs.x + b0[f0];
    float v1 = a1 + xs.x + b0[64 + f0];
    float v2 = a2 + xs.x + b0[128 + f0];
    float v3 = a3 + xs.x + b0[192 + f0];
    float v4 = a4 + xs.y + b0[f0 + 1];
    float v5 = a5 + xs.y + b0[64 + f0 + 1];
    float v6 = a6 + xs.y + b0[128 + f0 + 1];
    float v7 = a7 + xs.y + b0[192 + f0 + 1];
    v0 = v0 > 0.f ? v0 : expm1f(v0);
    v1 = v1 > 0.f ? v1 : expm1f(v1);
    v2 = v2 > 0.f ? v2 : expm1f(v2);
    v3 = v3 > 0.f ? v3 : expm1f(v3);
    v4 = v4 > 0.f ? v4 : expm1f(v4);
    v5 = v5 > 0.f ? v5 : expm1f(v5);
    v6 = v6 > 0.f ? v6 : expm1f(v6);
    v7 = v7 > 0.f ? v7 : expm1f(v7);
    uint4 o;
    o.x = (unsigned)f2b(v0) | ((unsigned)f2b(v1) << 16);
    o.y = (unsigned)f2b(v2) | ((unsigned)f2b(v3) << 16);
    o.z = (unsigned)f2b(v4) | ((unsigned)f2b(v5) << 16);
    o.w = (unsigned)f2b(v6) | ((unsigned)f2b(v7) << 16);
    *(uint4*)(out0b + (size_t)n * 256 + sl * 8) = o;
  }
}

// ====== Layer-1 MFMA GEMM: [N,256] x [256,144] (k-permuted B) =================
#define LDA1 264
__global__ __launch_bounds__(256) void k_mm1(
    const __hip_bfloat16* __restrict__ hsrc, const short* __restrict__ B1,
    const float* __restrict__ b1, __hip_bfloat16* __restrict__ proj1,
    float* __restrict__ out, float* __restrict__ s1, float* __restrict__ s2,
    float* __restrict__ s3) {
  __shared__ short As[64 * LDA1];
  const int t = threadIdx.x;
  const int lane = t & 63, w = t >> 6;
  const int base = blockIdx.x * 64;
  for (int q = 0; q < 8; ++q) {
    const int i = q * 256 + t;
    const int r = i >> 5;
    const int c = (i & 31) * 8;
    int rg = base + r;
    if (rg >= NNODES) rg = NNODES - 1;
    const float4 v = *(const float4*)((const short*)hsrc + (size_t)rg * 256 + c);
    *(float4*)(&As[r * LDA1 + c]) = v;
  }
  __syncthreads();
  const short8* B8 = (const short8*)B1;
  f32x4 acc[9];
#pragma unroll
  for (int g = 0; g < 9; ++g) acc[g] = (f32x4){0.f, 0.f, 0.f, 0.f};
  const int aoff = (w * 16 + (lane & 15)) * LDA1 + (lane >> 4) * 8;
#pragma unroll
  for (int s = 0; s < 8; ++s) {
    const short8 af = *(const short8*)(&As[aoff + s * 32]);
#pragma unroll
    for (int g = 0; g < 9; ++g) {
      const short8 bf = B8[(g * 8 + s) * 64 + lane];
      acc[g] = __builtin_amdgcn_mfma_f32_16x16x32_bf16(af, bf, acc[g], 0, 0, 0);
    }
  }
  const int r0 = base + w * 16 + (lane >> 4) * 4;
  const int cn = lane & 15;
#pragma unroll
  for (int g = 0; g < 4; ++g) {
    const int col = g * 16 + cn;
#pragma unroll
    for (int r = 0; r < 4; ++r) {
      const int row = r0 + r;
      if (row < NNODES)
        proj1[(size_t)row * 64 + col] = __float2bfloat16(acc[g][r]);
    }
  }
#pragma unroll
  for (int g = 4; g < 8; ++g) {
    const int col = (g - 4) * 16 + cn;
    const float bv = b1[col];
#pragma unroll
    for (int r = 0; r < 4; ++r) {
      const int row = r0 + r;
      if (row < NNODES) out[(size_t)row * 64 + col] = acc[g][r] + bv;
    }
  }
#pragma unroll
  for (int r = 0; r < 4; ++r) {
    const int row = r0 + r;
    if (row < NNODES) {
      if (cn == 0) s1[row] = acc[8][r];
      else if (cn == 1) s2[row] = acc[8][r];
      else if (cn == 2) s3[row] = acc[8][r];
    }
  }
}

// ====== Layer-1 exp-scores + denominator atomics ==============================
__global__ void k_esx1s(const int2* __restrict__ recA, const float* __restrict__ s1,
                        const float* __restrict__ s2, const float* __restrict__ s3,
                        float* __restrict__ es1, float* __restrict__ sums1) {
  const int j = blockIdx.x * 256 + threadIdx.x;
  if (j >= 2 * NEDGES) return;
  const int2 rec = recA[j];
  const int drug = rec.x & 0x1FFFF;
  const int o = rec.y & 0x1FFFF;
  const int n = dec_n(rec);
  const int role = ((unsigned)rec.y >> 19) & 1;
  float s = s1[drug] + s2[role ? o : n] + s3[role ? n : o];
  s = s > 0.f ? s : 0.2f * s;
  const float e = __expf(s);
  es1[j] = e;
  atomicAdd(&sums1[n], e);
}

// ========== Layer-1 aggregate, wave/node, FUSED normalization =================
// 8 lanes per slot (uint4 = 16B/lane), 8 slots per wave-step; group-combine via
// __shfl_xor butterfly (8,16,32).
__global__ __launch_bounds__(256) void k_agg1(
    const int* __restrict__ offs, const int2* __restrict__ recA,
    const float* __restrict__ es1, const float* __restrict__ sums,
    const __hip_bfloat16* __restrict__ proj1, float* __restrict__ dout) {
  const int lane = threadIdx.x & 63, wid = threadIdx.x >> 6;
  const int n = blockIdx.x * 4 + wid;
  if (n >= NNODES) return;
  const int beg = offs[n], end = offs[n + 1];
  if (beg == end) return;  // dout row already holds skip+bias from k_mm1
  const int g = lane >> 3;  // slot group 0..7
  const int li = lane & 7;  // features li*8 .. li*8+7
  const float sn = sums[n];
  float a0 = 0.f, a1 = 0.f, a2 = 0.f, a3 = 0.f;
  float a4 = 0.f, a5 = 0.f, a6 = 0.f, a7 = 0.f;

#define SLOT(J, LIVE)                                                          \
  {                                                                            \
    const int jj = (J) + g;                                                    \
    const bool lv = (LIVE);                                                    \
    const int js = lv ? jj : beg;                                              \
    const int2 rec = recA[js];                                                 \
    const int dd = rec.x & 0x1FFFF;                                            \
    const int o = rec.y & 0x1FFFF;                                             \
    const float e = es1[js];                                                   \
    const float t =                                                            \
        (lv ? e : 0.f) * __builtin_amdgcn_rcpf(sn + sums[o] + 1e-16f);         \
    const uint4 r = *(const uint4*)(proj1 + (size_t)dd * 64 + li * 8);         \
    a0 = fmaf(bits2f_lo(r.x), t, a0);                                          \
    a1 = fmaf(bits2f_hi(r.x), t, a1);                                          \
    a2 = fmaf(bits2f_lo(r.y), t, a2);                                          \
    a3 = fmaf(bits2f_hi(r.y), t, a3);                                          \
    a4 = fmaf(bits2f_lo(r.z), t, a4);                                          \
    a5 = fmaf(bits2f_hi(r.z), t, a5);                                          \
    a6 = fmaf(bits2f_lo(r.w), t, a6);                                          \
    a7 = fmaf(bits2f_hi(r.w), t, a7);                                          \
  }

  int j = beg;
  for (; j + 8 <= end; j += 8) SLOT(j, true)
  for (; j < end; j += 8) SLOT(j, jj < end)
#undef SLOT

  // butterfly-reduce across the 8 slot groups
#define RED(m)                                                                 \
  a0 += __shfl_xor(a0, m); a1 += __shfl_xor(a1, m);                            \
  a2 += __shfl_xor(a2, m); a3 += __shfl_xor(a3, m);                            \
  a4 += __shfl_xor(a4, m); a5 += __shfl_xor(a5, m);                            \
  a6 += __shfl_xor(a6, m); a7 += __shfl_xor(a7, m);
  RED(8) RED(16) RED(32)
#undef RED

  if (g == 0) {
    float4* dp = (float4*)(dout + (size_t)n * 64 + li * 8);
    float4 d0 = dp[0], d1 = dp[1];
    d0.x += a0; d0.y += a1; d0.z += a2; d0.w += a3;
    d1.x += a4; d1.y += a5; d1.z += a6; d1.w += a7;
    dp[0] = d0;
    dp[1] = d1;
  }
}

extern "C" void kernel_launch(void* const* d_in, const int* in_sizes, int n_in,
                              void* d_out, int out_size, void* d_ws, size_t ws_size,
                              hipStream_t stream) {
  const float* x = (const float*)d_in[0];
  const int* ei = (const int*)d_in[1];
  const float* W0 = (const float*)d_in[2];
  const float* a10 = (const float*)d_in[3];
  const float* a20 = (const float*)d_in[4];
  const float* a30 = (const float*)d_in[5];
  // d_in[6] = Wskip0: unused (layer-0 skip is identity, F==DIN)
  const float* b0 = (const float*)d_in[7];
  const float* W1 = (const float*)d_in[8];
  const float* a11 = (const float*)d_in[9];
  const float* a21 = (const float*)d_in[10];
  const float* a31 = (const float*)d_in[11];
  const float* Wskip1 = (const float*)d_in[12];
  const float* b1 = (const float*)d_in[13];
  float* out = (float*)d_out;

  // ---- Workspace layout ----
  __hip_bfloat16* proj0 = (__hip_bfloat16*)d_ws;         // N*256 bf16 (head-ilv)
  __hip_bfloat16* out0b = proj0 + (size_t)NNODES * 256;  // N*256 bf16 (head-ilv)
  float* s1_0 = (float*)(out0b + (size_t)NNODES * 256);  // N*4 x3
  float* s2_0 = s1_0 + (size_t)NNODES * 4;
  float* s3_0 = s2_0 + (size_t)NNODES * 4;
  // --- contiguous zeroed region: sums0 | sums1 | (deg,cursor,desc in esx0) ---
  float* sums0 = s3_0 + (size_t)NNODES * 4;            // N*4 f32
  float* sums1 = sums0 + (size_t)NNODES * 4;           // N f32
  float* esx0 = sums1 + NNODES;                        // 2E*4 f32
  int* deg = (int*)esx0;                               // N int (alias)
  int* cursor = deg + NNODES;                          // N int (alias)
  int* desc = cursor + NNODES;                         // 392 ints (alias)
  // --- end zeroed region (7N+392 ints from sums0) ---
  int2* recA = (int2*)(esx0 + (size_t)2 * NEDGES * 4); // 2E int2 (packed)
  int* offs = (int*)(recA + 2 * NEDGES);               // N+16
  float* s1_1 = (float*)(offs + NNODES + 16);          // N x3
  float* s2_1 = s1_1 + NNODES;
  float* s3_1 = s2_1 + NNODES;
  __hip_bfloat16* B0swz = (__hip_bfloat16*)(s3_1 + NNODES);  // 17408 bf16
  __hip_bfloat16* B1swz = B0swz + 17408;               // 36864 bf16

  __hip_bfloat16* proj1 = proj0;  // aliases proj0 (dead after k_agg0w)
  float* es1 = esx0;              // layer-1 exp slots (esx0 dead after k_agg0w)

  // ---- one memset: sums0 + sums1 + deg + cursor + desc = 7N+392 ints ----
  hipMemsetAsync(sums0, 0, (size_t)(7 * NNODES + 392) * 4, stream);

  // ---- fused weight prep + degree count ----
  k_prepdeg<<<212 + (2 * NEDGES + 255) / 256, 256, 0, stream>>>(
      W0, a10, a20, a30, W1, Wskip1, a11, a21, a31, B0swz, B1swz, ei, deg);

  // ---- fused lookback-scan (CSR offsets) + layer-0 MFMA GEMM ----
  k_scanmm0<<<NB_SCAN + (NNODES + 63) / 64, 256, 0, stream>>>(
      deg, offs, cursor, desc, x, (const short*)B0swz, proj0, s1_0, s2_0, s3_0);

  // ---- CSR fill (packed records) ----
  const int NBS = (2 * NEDGES + 255) / 256;
  k_fill3p<<<NBS, 256, 0, stream>>>(ei, cursor, recA);

  // ---- Layer 0: slot exp + atomic sums -> fused(att+aggregate) ----
  k_esx0s<<<NBS, 256, 0, stream>>>(recA, s1_0, s2_0, s3_0, esx0, sums0);
  k_agg0w<<<(NNODES + 3) / 4, 256, 0, stream>>>(offs, recA, esx0, sums0, proj0,
                                                x, b0, out0b);

  // ---- Layer 1: MFMA GEMM -> slot exp + atomic sums -> fused(att+agg) ----
  k_mm1<<<(NNODES + 63) / 64, 256, 0, stream>>>(out0b, (const short*)B1swz, b1,
                                                proj1, out, s1_1, s2_1, s3_1);
  k_esx1s<<<NBS, 256, 0, stream>>>(recA, s1_1, s2_1, s3_1, es1, sums1);
  k_agg1<<<(NNODES + 3) / 4, 256, 0, stream>>>(offs, recA, es1, sums1, proj1,
                                               out);
}

// Round 7
// 483.006 us; speedup vs baseline: 1.5089x; 1.5089x over previous
//
#include <hip/hip_runtime.h>
#include <hip/hip_bf16.h>
#include <math.h>

#define NNODES 100000
#define NEDGES 500000
#define NB_SCAN 391  // ceil(NNODES/256)

typedef __attribute__((ext_vector_type(8))) short short8;
typedef __attribute__((ext_vector_type(4))) float f32x4;

__device__ __forceinline__ float bf2f(__hip_bfloat16 v) {
  return __bfloat162float(v);
}
__device__ __forceinline__ unsigned short f2b(float f) {
  __hip_bfloat16 h = __float2bfloat16(f);
  return *(unsigned short*)&h;
}
__device__ __forceinline__ float bits2f_lo(unsigned u) {
  return __uint_as_float(u << 16);
}
__device__ __forceinline__ float bits2f_hi(unsigned u) {
  return __uint_as_float(u & 0xffff0000u);
}
// packed slot record: x = drug | (n&0x7FFF)<<17 ; y = other | (n>>15)<<17 | role<<19
__device__ __forceinline__ int dec_n(int2 r) {
  return (int)(((unsigned)r.x >> 17) | ((((unsigned)r.y >> 17) & 3u) << 15));
}

// ========== Fused weight-prep (blocks 0..211) + degree count (rest) ===========
__global__ void k_prepdeg(const float* __restrict__ W0, const float* __restrict__ a10,
                          const float* __restrict__ a20, const float* __restrict__ a30,
                          const float* __restrict__ W1, const float* __restrict__ Wsk,
                          const float* __restrict__ a11, const float* __restrict__ a21,
                          const float* __restrict__ a31,
                          __hip_bfloat16* __restrict__ B0,
                          __hip_bfloat16* __restrict__ B1,
                          const int* __restrict__ ei, int* __restrict__ deg) {
  if (blockIdx.x >= 212) {
    const int idx = (blockIdx.x - 212) * 256 + threadIdx.x;
    if (idx < 2 * NEDGES) atomicAdd(&deg[ei[NEDGES + idx]], 1);
    return;
  }
  if (blockIdx.x < 68) {
    const int t = blockIdx.x * 256 + threadIdx.x;  // < 17408
    const int j = t & 7, l = (t >> 3) & 63, s = (t >> 9) & 1, g = t >> 10;
    const int k = s * 32 + ((l >> 4) << 3) + j;
    const int col = g * 16 + (l & 15);
    float v = 0.f;
    if (col < 256) {
      v = W0[col * 64 + k];
    } else if (col < 268) {
      const int idx = col - 256;
      const int r = idx >> 2, h = idx & 3;
      const float* av = (r == 0) ? a10 : (r == 1) ? a20 : a30;
      for (int f = 0; f < 64; ++f)
        v = fmaf(av[h * 64 + f], W0[(h * 64 + f) * 64 + k], v);
    }
    B0[t] = __float2bfloat16(v);
  } else {
    const int t = (blockIdx.x - 68) * 256 + threadIdx.x;  // < 36864
    const int j = t & 7, l = (t >> 3) & 63, s = (t >> 9) & 7, g = t >> 12;
    const int kp = s * 32 + ((l >> 4) << 3) + j;
    const int k = (kp & 3) * 64 + (kp >> 2);  // permuted -> original (head-ilv A)
    const int col = g * 16 + (l & 15);
    float v = 0.f;
    if (col < 64) {
      v = W1[col * 256 + k];
    } else if (col < 128) {
      v = Wsk[(col - 64) * 256 + k];
    } else if (col < 131) {
      const int r = col - 128;
      const float* av = (r == 0) ? a11 : (r == 1) ? a21 : a31;
      for (int f = 0; f < 64; ++f) v = fmaf(av[f], W1[f * 256 + k], v);
    }
    B1[t] = __float2bfloat16(v);
  }
}

// ====== Fused: blocks 0..390 = wave-parallel lookback scan; rest = mm0 ========
#define FLG_AGG (1 << 30)
#define FLG_PRE (2 << 30)
#define VMASK 0x3FFFFFFF
#define LDA0 72
__global__ __launch_bounds__(256) void k_scanmm0(
    const int* __restrict__ deg, int* __restrict__ offs, int* __restrict__ cursor,
    int* __restrict__ desc,  // desc[0]=ticket, desc[1..NB_SCAN]=status
    const float* __restrict__ x, const short* __restrict__ B0,
    __hip_bfloat16* __restrict__ proj0, float* __restrict__ s1,
    float* __restrict__ s2, float* __restrict__ s3) {
  __shared__ __hip_bfloat16 As[64 * LDA0];
  __shared__ int sh[256];
  __shared__ int sbid, sexc;
  const int t = threadIdx.x;

  if (blockIdx.x < NB_SCAN) {
    // ---------------- decoupled-lookback exclusive scan of deg ----------------
    if (t == 0) sbid = atomicAdd(&desc[0], 1);
    __syncthreads();
    const int b = sbid;
    const int i = b * 256 + t;
    const int v = (i < NNODES) ? deg[i] : 0;
    sh[t] = v;
    __syncthreads();
    for (int d = 1; d < 256; d <<= 1) {
      const int add = (t >= d) ? sh[t - d] : 0;
      __syncthreads();
      sh[t] += add;
      __syncthreads();
    }
    const int total = sh[255];
    int* st = desc + 1;
    if (t == 0) {
      __hip_atomic_store(&st[b], total | (b == 0 ? FLG_PRE : FLG_AGG),
                         __ATOMIC_RELEASE, __HIP_MEMORY_SCOPE_AGENT);
      if (b == 0) sexc = 0;
    }
    if (b > 0 && t < 64) {
      // wave 0: read 64 predecessor statuses per step
      int exc = 0;
      int p = b - 1;
      while (true) {
        const int idx = p - t;
        int d;
        if (idx >= 0) {
          d = __hip_atomic_load(&st[idx], __ATOMIC_ACQUIRE,
                                __HIP_MEMORY_SCOPE_AGENT);
        } else {
          d = FLG_PRE;  // synthetic prefix=0 beyond block 0 (never reached)
        }
        const unsigned long long pre = __ballot(d & FLG_PRE);
        const unsigned long long zer = __ballot(d == 0);
        if (pre) {
          const int L = __ffsll(pre) - 1;  // nearest PRE (lowest lane)
          const unsigned long long lowmask =
              (L >= 63) ? ~0ULL : ((1ULL << (L + 1)) - 1);
          if (zer & lowmask) {  // unposted gap before the PRE -> retry
            __builtin_amdgcn_s_sleep(1);
            continue;
          }
          int c = (t <= L) ? (d & VMASK) : 0;
          for (int m = 1; m < 64; m <<= 1) c += __shfl_xor(c, m);
          exc += c;
          break;
        }
        if (zer) {  // any unposted in window -> retry
          __builtin_amdgcn_s_sleep(1);
          continue;
        }
        int c = d & VMASK;  // all 64 are AGG: take the window, walk back
        for (int m = 1; m < 64; m <<= 1) c += __shfl_xor(c, m);
        exc += c;
        p -= 64;
      }
      if (t == 0) {
        __hip_atomic_store(&st[b], (exc + total) | FLG_PRE, __ATOMIC_RELEASE,
                           __HIP_MEMORY_SCOPE_AGENT);
        sexc = exc;
      }
    }
    __syncthreads();
    const int exc = sexc;
    if (i < NNODES) {
      const int o = exc + sh[t] - v;
      offs[i] = o;
      cursor[i] = o;
    }
    if (b == 0 && t == 0) offs[NNODES] = 2 * NEDGES;
    return;
  }

  // ---------------- Layer-0 MFMA GEMM: [N,64] x [64,272] ----------------------
  // proj0 stored HEAD-INTERLEAVED: proj0[n*256 + f*4 + h]; packed uint2 stores.
  const int lane = t & 63, w = t >> 6;
  const int base = (blockIdx.x - NB_SCAN) * 64;
  for (int q = 0; q < 4; ++q) {
    const int i = q * 256 + t;
    const int r = i >> 4;
    const int c4 = i & 15;
    int rg = base + r;
    if (rg >= NNODES) rg = NNODES - 1;
    const float4 v = ((const float4*)(x + (size_t)rg * 64))[c4];
    __hip_bfloat16* dst = &As[r * LDA0 + c4 * 4];
    dst[0] = __float2bfloat16(v.x);
    dst[1] = __float2bfloat16(v.y);
    dst[2] = __float2bfloat16(v.z);
    dst[3] = __float2bfloat16(v.w);
  }
  __syncthreads();
  const short8* B8 = (const short8*)B0;
  f32x4 acc[17];
#pragma unroll
  for (int g = 0; g < 17; ++g) acc[g] = (f32x4){0.f, 0.f, 0.f, 0.f};
  const int aoff = (w * 16 + (lane & 15)) * LDA0 + (lane >> 4) * 8;
#pragma unroll
  for (int s = 0; s < 2; ++s) {
    const short8 af = *(const short8*)(&As[aoff + s * 32]);
#pragma unroll
    for (int g = 0; g < 17; ++g) {
      const short8 bf = B8[(g * 2 + s) * 64 + lane];
      acc[g] = __builtin_amdgcn_mfma_f32_16x16x32_bf16(af, bf, acc[g], 0, 0, 0);
    }
  }
  const int r0 = base + w * 16 + (lane >> 4) * 4;
  const int cn = lane & 15;
  // packed epilogue: heads h of feature f=g*16+cn are acc[g+4h]
#pragma unroll
  for (int g = 0; g < 4; ++g) {
    const int f = g * 16 + cn;
#pragma unroll
    for (int r = 0; r < 4; ++r) {
      const int row = r0 + r;
      if (row < NNODES) {
        uint2 o;
        o.x = (unsigned)f2b(acc[g][r]) | ((unsigned)f2b(acc[g + 4][r]) << 16);
        o.y = (unsigned)f2b(acc[g + 8][r]) | ((unsigned)f2b(acc[g + 12][r]) << 16);
        *(uint2*)(proj0 + (size_t)row * 256 + f * 4) = o;
      }
    }
  }
#pragma unroll
  for (int r = 0; r < 4; ++r) {
    const int row = r0 + r;
    if (row < NNODES) {
      if (cn < 4) s1[row * 4 + cn] = acc[16][r];
      else if (cn < 8) s2[row * 4 + (cn - 4)] = acc[16][r];
      else if (cn < 12) s3[row * 4 + (cn - 8)] = acc[16][r];
    }
  }
}

// Fill packed slot records (no rcvA).
__global__ void k_fill3p(const int* __restrict__ ei, int* __restrict__ cursor,
                         int2* __restrict__ recA) {
  const int idx = blockIdx.x * 256 + threadIdx.x;
  if (idx >= 2 * NEDGES) return;
  const int n = ei[NEDGES + idx];
  const int e = (idx < NEDGES) ? idx : idx - NEDGES;
  const int drug = ei[e];
  const int other = (idx < NEDGES) ? ei[2 * NEDGES + e] : ei[NEDGES + e];
  const int role = (idx < NEDGES) ? 0 : 1;
  const int pos = atomicAdd(&cursor[n], 1);
  const int px = drug | ((n & 0x7FFF) << 17);
  const int py = other | (((n >> 15) & 3) << 17) | (role << 19);
  recA[pos] = make_int2(px, py);
}

// ====== Layer-0 exp-scores, SLOT-PARALLEL (no atomics) ========================
__global__ void k_esx0p(const int2* __restrict__ recA, const float* __restrict__ s1,
                        const float* __restrict__ s2, const float* __restrict__ s3,
                        float* __restrict__ esx) {
  const int j = blockIdx.x * 256 + threadIdx.x;
  if (j >= 2 * NEDGES) return;
  const int2 rec = recA[j];
  const int drug = rec.x & 0x1FFFF;
  const int o = rec.y & 0x1FFFF;
  const int n = dec_n(rec);
  const int role = ((unsigned)rec.y >> 19) & 1;
  const float4 A = ((const float4*)s1)[drug];
  const float4 T = ((const float4*)s2)[role ? o : n];
  const float4 D = ((const float4*)s3)[role ? n : o];
  float4 es;
  float s;
  s = A.x + T.x + D.x; s = s > 0.f ? s : 0.2f * s; es.x = __expf(s);
  s = A.y + T.y + D.y; s = s > 0.f ? s : 0.2f * s; es.y = __expf(s);
  s = A.z + T.z + D.z; s = s > 0.f ? s : 0.2f * s; es.z = __expf(s);
  s = A.w + T.w + D.w; s = s > 0.f ? s : 0.2f * s; es.w = __expf(s);
  ((float4*)esx)[j] = es;
}

// ====== Layer-0 denominator sums: per node, sequential esx reads ==============
__global__ void k_sums0n(const int* __restrict__ offs, const float* __restrict__ esx,
                         float* __restrict__ sums) {
  const int n = blockIdx.x * 256 + threadIdx.x;
  if (n >= NNODES) return;
  const int beg = offs[n], end = offs[n + 1];
  float4 acc = make_float4(0.f, 0.f, 0.f, 0.f);
  for (int j = beg; j < end; ++j) {
    const float4 v = ((const float4*)esx)[j];
    acc.x += v.x; acc.y += v.y; acc.z += v.z; acc.w += v.w;
  }
  ((float4*)sums)[n] = acc;
}

// ====== Layer-0 aggregate, wave/node, FUSED normalization =====================
// 32 lanes per slot (uint4 = 16B/lane), 2 slots per wave-step; half-combine via
// __shfl_xor(32). att computed on the fly: esx[j]*rcp(sums[n]+sums[o]).
__global__ __launch_bounds__(256) void k_agg0w(
    const int* __restrict__ offs, const int2* __restrict__ recA,
    const float* __restrict__ esx, const float* __restrict__ sums,
    const __hip_bfloat16* __restrict__ proj0, const float* __restrict__ x,
    const float* __restrict__ b0, __hip_bfloat16* __restrict__ out0b) {
  const int lane = threadIdx.x & 63, wid = threadIdx.x >> 6;
  const int n = blockIdx.x * 4 + wid;
  if (n >= NNODES) return;
  const int beg = offs[n], end = offs[n + 1];
  const int h = lane >> 5;   // which slot of the pair
  const int sl = lane & 31;  // features 2*sl, 2*sl+1 (x 4 heads)
  const float4 sn = ((const float4*)sums)[n];
  float a0 = 0.f, a1 = 0.f, a2 = 0.f, a3 = 0.f;
  float a4 = 0.f, a5 = 0.f, a6 = 0.f, a7 = 0.f;

#define PAIR(J, LIVE)                                                          \
  {                                                                            \
    const int jj = (J) + h;                                                    \
    const bool lv = (LIVE);                                                    \
    const int js = lv ? jj : beg;                                              \
    const int2 rec = recA[js];                                                 \
    const int dd = rec.x & 0x1FFFF;                                            \
    const int o = rec.y & 0x1FFFF;                                             \
    const float4 e = ((const float4*)esx)[js];                                 \
    const float4 so = ((const float4*)sums)[o];                                \
    const uint4 r = *(const uint4*)(proj0 + (size_t)dd * 256 + sl * 8);        \
    const float lm = lv ? 1.f : 0.f;                                           \
    const float t0 = lm * e.x * __builtin_amdgcn_rcpf(sn.x + so.x + 1e-16f);   \
    const float t1 = lm * e.y * __builtin_amdgcn_rcpf(sn.y + so.y + 1e-16f);   \
    const float t2 = lm * e.z * __builtin_amdgcn_rcpf(sn.z + so.z + 1e-16f);   \
    const float t3 = lm * e.w * __builtin_amdgcn_rcpf(sn.w + so.w + 1e-16f);   \
    a0 = fmaf(bits2f_lo(r.x), t0, a0);                                         \
    a1 = fmaf(bits2f_hi(r.x), t1, a1);                                         \
    a2 = fmaf(bits2f_lo(r.y), t2, a2);                                         \
    a3 = fmaf(bits2f_hi(r.y), t3, a3);                                         \
    a4 = fmaf(bits2f_lo(r.z), t0, a4);                                         \
    a5 = fmaf(bits2f_hi(r.z), t1, a5);                                         \
    a6 = fmaf(bits2f_lo(r.w), t2, a6);                                         \
    a7 = fmaf(bits2f_hi(r.w), t3, a7);                                         \
  }

  int j = beg;
  for (; j + 4 <= end; j += 4) {
    PAIR(j, true)
    PAIR(j + 2, true)
  }
  for (; j < end; j += 2) PAIR(j, jj < end)
#undef PAIR

  // combine the two slot-halves
  a0 += __shfl_xor(a0, 32); a1 += __shfl_xor(a1, 32);
  a2 += __shfl_xor(a2, 32); a3 += __shfl_xor(a3, 32);
  a4 += __shfl_xor(a4, 32); a5 += __shfl_xor(a5, 32);
  a6 += __shfl_xor(a6, 32); a7 += __shfl_xor(a7, 32);

  if (h == 0) {
    const float2 xs = ((const float2*)(x + (size_t)n * 64))[sl];
    const int f0 = sl * 2;
    float v0 = a0 + xs.x + b0[f0];
    float v1 = a1 + xs.x + b0[64 + f0];
    float v2 = a2 + xs.x + b0[128 + f0];
    float v3 = a3 + xs.x + b0[192 + f0];
    float v4 = a4 + xs.y + b0[f0 + 1];
    float v5 = a5 + xs.y + b0[64 + f0 + 1];
    float v6 = a6 + xs.y + b0[128 + f0 + 1];
    float v7 = a7 + xs.y + b0[192 + f0 + 1];
    v0 = v0 > 0.f ? v0 : expm1f(v0);
    v1 = v1 > 0.f ? v1 : expm1f(v1);
    v2 = v2 > 0.f ? v2 : expm1f(v2);
    v3 = v3 > 0.f ? v3 : expm1f(v3);
    v4 = v4 > 0.f ? v4 : expm1f(v4);
    v5 = v5 > 0.f ? v5 : expm1f(v5);
    v6 = v6 > 0.f ? v6 : expm1f(v6);
    v7 = v7 > 0.f ? v7 : expm1f(v7);
    uint4 o;
    o.x = (unsigned)f2b(v0) | ((unsigned)f2b(v1) << 16);
    o.y = (unsigned)f2b(v2) | ((unsigned)f2b(v3) << 16);
    o.z = (unsigned)f2b(v4) | ((unsigned)f2b(v5) << 16);
    o.w = (unsigned)f2b(v6) | ((unsigned)f2b(v7) << 16);
    *(uint4*)(out0b + (size_t)n * 256 + sl * 8) = o;
  }
}

// ====== Layer-1 MFMA GEMM: [N,256] x [256,144] (k-permuted B) =================
#define LDA1 264
__global__ __launch_bounds__(256) void k_mm1(
    const __hip_bfloat16* __restrict__ hsrc, const short* __restrict__ B1,
    const float* __restrict__ b1, __hip_bfloat16* __restrict__ proj1,
    float* __restrict__ out, float* __restrict__ s1, float* __restrict__ s2,
    float* __restrict__ s3) {
  __shared__ short As[64 * LDA1];
  const int t = threadIdx.x;
  const int lane = t & 63, w = t >> 6;
  const int base = blockIdx.x * 64;
  for (int q = 0; q < 8; ++q) {
    const int i = q * 256 + t;
    const int r = i >> 5;
    const int c = (i & 31) * 8;
    int rg = base + r;
    if (rg >= NNODES) rg = NNODES - 1;
    const float4 v = *(const float4*)((const short*)hsrc + (size_t)rg * 256 + c);
    *(float4*)(&As[r * LDA1 + c]) = v;
  }
  __syncthreads();
  const short8* B8 = (const short8*)B1;
  f32x4 acc[9];
#pragma unroll
  for (int g = 0; g < 9; ++g) acc[g] = (f32x4){0.f, 0.f, 0.f, 0.f};
  const int aoff = (w * 16 + (lane & 15)) * LDA1 + (lane >> 4) * 8;
#pragma unroll
  for (int s = 0; s < 8; ++s) {
    const short8 af = *(const short8*)(&As[aoff + s * 32]);
#pragma unroll
    for (int g = 0; g < 9; ++g) {
      const short8 bf = B8[(g * 8 + s) * 64 + lane];
      acc[g] = __builtin_amdgcn_mfma_f32_16x16x32_bf16(af, bf, acc[g], 0, 0, 0);
    }
  }
  const int r0 = base + w * 16 + (lane >> 4) * 4;
  const int cn = lane & 15;
#pragma unroll
  for (int g = 0; g < 4; ++g) {
    const int col = g * 16 + cn;
#pragma unroll
    for (int r = 0; r < 4; ++r) {
      const int row = r0 + r;
      if (row < NNODES)
        proj1[(size_t)row * 64 + col] = __float2bfloat16(acc[g][r]);
    }
  }
#pragma unroll
  for (int g = 4; g < 8; ++g) {
    const int col = (g - 4) * 16 + cn;
    const float bv = b1[col];
#pragma unroll
    for (int r = 0; r < 4; ++r) {
      const int row = r0 + r;
      if (row < NNODES) out[(size_t)row * 64 + col] = acc[g][r] + bv;
    }
  }
#pragma unroll
  for (int r = 0; r < 4; ++r) {
    const int row = r0 + r;
    if (row < NNODES) {
      if (cn == 0) s1[row] = acc[8][r];
      else if (cn == 1) s2[row] = acc[8][r];
      else if (cn == 2) s3[row] = acc[8][r];
    }
  }
}

// ====== Layer-1 exp-scores, SLOT-PARALLEL (no atomics) ========================
__global__ void k_esx1p(const int2* __restrict__ recA, const float* __restrict__ s1,
                        const float* __restrict__ s2, const float* __restrict__ s3,
                        float* __restrict__ es1) {
  const int j = blockIdx.x * 256 + threadIdx.x;
  if (j >= 2 * NEDGES) return;
  const int2 rec = recA[j];
  const int drug = rec.x & 0x1FFFF;
  const int o = rec.y & 0x1FFFF;
  const int n = dec_n(rec);
  const int role = ((unsigned)rec.y >> 19) & 1;
  float s = s1[drug] + s2[role ? o : n] + s3[role ? n : o];
  s = s > 0.f ? s : 0.2f * s;
  es1[j] = __expf(s);
}

// ====== Layer-1 denominator sums: per node, sequential ========================
__global__ void k_sums1n(const int* __restrict__ offs, const float* __restrict__ es1,
                         float* __restrict__ sums) {
  const int n = blockIdx.x * 256 + threadIdx.x;
  if (n >= NNODES) return;
  const int beg = offs[n], end = offs[n + 1];
  float acc = 0.f;
  for (int j = beg; j < end; ++j) acc += es1[j];
  sums[n] = acc;
}

// ========== Layer-1 aggregate, wave/node, FUSED normalization =================
// 8 lanes per slot (uint4 = 16B/lane), 8 slots per wave-step; group-combine via
// __shfl_xor butterfly (8,16,32).
__global__ __launch_bounds__(256) void k_agg1(
    const int* __restrict__ offs, const int2* __restrict__ recA,
    const float* __restrict__ es1, const float* __restrict__ sums,
    const __hip_bfloat16* __restrict__ proj1, float* __restrict__ dout) {
  const int lane = threadIdx.x & 63, wid = threadIdx.x >> 6;
  const int n = blockIdx.x * 4 + wid;
  if (n >= NNODES) return;
  const int beg = offs[n], end = offs[n + 1];
  if (beg == end) return;  // dout row already holds skip+bias from k_mm1
  const int g = lane >> 3;  // slot group 0..7
  const int li = lane & 7;  // features li*8 .. li*8+7
  const float sn = sums[n];
  float a0 = 0.f, a1 = 0.f, a2 = 0.f, a3 = 0.f;
  float a4 = 0.f, a5 = 0.f, a6 = 0.f, a7 = 0.f;

#define SLOT(J, LIVE)                                                          \
  {                                                                            \
    const int jj = (J) + g;                                                    \
    const bool lv = (LIVE);                                                    \
    const int js = lv ? jj : beg;                                              \
    const int2 rec = recA[js];                                                 \
    const int dd = rec.x & 0x1FFFF;                                            \
    const int o = rec.y & 0x1FFFF;                                             \
    const float e = es1[js];                                                   \
    const float t =                                                            \
        (lv ? e : 0.f) * __builtin_amdgcn_rcpf(sn + sums[o] + 1e-16f);         \
    const uint4 r = *(const uint4*)(proj1 + (size_t)dd * 64 + li * 8);         \
    a0 = fmaf(bits2f_lo(r.x), t, a0);                                          \
    a1 = fmaf(bits2f_hi(r.x), t, a1);                                          \
    a2 = fmaf(bits2f_lo(r.y), t, a2);                                          \
    a3 = fmaf(bits2f_hi(r.y), t, a3);                                          \
    a4 = fmaf(bits2f_lo(r.z), t, a4);                                          \
    a5 = fmaf(bits2f_hi(r.z), t, a5);                                          \
    a6 = fmaf(bits2f_lo(r.w), t, a6);                                          \
    a7 = fmaf(bits2f_hi(r.w), t, a7);                                          \
  }

  int j = beg;
  for (; j + 8 <= end; j += 8) SLOT(j, true)
  for (; j < end; j += 8) SLOT(j, jj < end)
#undef SLOT

  // butterfly-reduce across the 8 slot groups
#define RED(m)                                                                 \
  a0 += __shfl_xor(a0, m); a1 += __shfl_xor(a1, m);                            \
  a2 += __shfl_xor(a2, m); a3 += __shfl_xor(a3, m);                            \
  a4 += __shfl_xor(a4, m); a5 += __shfl_xor(a5, m);                            \
  a6 += __shfl_xor(a6, m); a7 += __shfl_xor(a7, m);
  RED(8) RED(16) RED(32)
#undef RED

  if (g == 0) {
    float4* dp = (float4*)(dout + (size_t)n * 64 + li * 8);
    float4 d0 = dp[0], d1 = dp[1];
    d0.x += a0; d0.y += a1; d0.z += a2; d0.w += a3;
    d1.x += a4; d1.y += a5; d1.z += a6; d1.w += a7;
    dp[0] = d0;
    dp[1] = d1;
  }
}

extern "C" void kernel_launch(void* const* d_in, const int* in_sizes, int n_in,
                              void* d_out, int out_size, void* d_ws, size_t ws_size,
                              hipStream_t stream) {
  const float* x = (const float*)d_in[0];
  const int* ei = (const int*)d_in[1];
  const float* W0 = (const float*)d_in[2];
  const float* a10 = (const float*)d_in[3];
  const float* a20 = (const float*)d_in[4];
  const float* a30 = (const float*)d_in[5];
  // d_in[6] = Wskip0: unused (layer-0 skip is identity, F==DIN)
  const float* b0 = (const float*)d_in[7];
  const float* W1 = (const float*)d_in[8];
  const float* a11 = (const float*)d_in[9];
  const float* a21 = (const float*)d_in[10];
  const float* a31 = (const float*)d_in[11];
  const float* Wskip1 = (const float*)d_in[12];
  const float* b1 = (const float*)d_in[13];
  float* out = (float*)d_out;

  // ---- Workspace layout ----
  __hip_bfloat16* proj0 = (__hip_bfloat16*)d_ws;         // N*256 bf16 (head-ilv)
  __hip_bfloat16* out0b = proj0 + (size_t)NNODES * 256;  // N*256 bf16 (head-ilv)
  float* s1_0 = (float*)(out0b + (size_t)NNODES * 256);  // N*4 x3
  float* s2_0 = s1_0 + (size_t)NNODES * 4;
  float* s3_0 = s2_0 + (size_t)NNODES * 4;
  float* sums0 = s3_0 + (size_t)NNODES * 4;            // N*4
  float* esx0 = sums0 + (size_t)NNODES * 4;            // 2E*4
  int2* recA = (int2*)(esx0 + (size_t)2 * NEDGES * 4); // 2E int2 (packed)
  int* offs = (int*)(recA + 2 * NEDGES);               // N+16
  float* s1_1 = (float*)(offs + NNODES + 16);          // N x3
  float* s2_1 = s1_1 + NNODES;
  float* s3_1 = s2_1 + NNODES;
  float* sums1 = s3_1 + NNODES;                        // N
  __hip_bfloat16* B0swz = (__hip_bfloat16*)(sums1 + NNODES);  // 17408 bf16
  __hip_bfloat16* B1swz = B0swz + 17408;               // 36864 bf16
  // CSR-build int scratch aliases esx0 (dead until k_esx0p):
  int* deg = (int*)esx0;                               // N int
  int* cursor = deg + NNODES;                          // N int
  int* desc = cursor + NNODES;                         // 392 ints (ticket+status)

  __hip_bfloat16* proj1 = proj0;  // aliases proj0 (dead after k_agg0w)
  float* es1 = esx0;              // layer-1 exp slots (esx0 dead after k_agg0w)

  // ---- one memset: deg + cursor + desc ----
  hipMemsetAsync(deg, 0, (size_t)(2 * NNODES + 392) * 4, stream);

  // ---- fused weight prep + degree count ----
  k_prepdeg<<<212 + (2 * NEDGES + 255) / 256, 256, 0, stream>>>(
      W0, a10, a20, a30, W1, Wskip1, a11, a21, a31, B0swz, B1swz, ei, deg);

  // ---- fused lookback-scan (CSR offsets) + layer-0 MFMA GEMM ----
  k_scanmm0<<<NB_SCAN + (NNODES + 63) / 64, 256, 0, stream>>>(
      deg, offs, cursor, desc, x, (const short*)B0swz, proj0, s1_0, s2_0, s3_0);

  // ---- CSR fill (packed records) ----
  const int NBS = (2 * NEDGES + 255) / 256;
  k_fill3p<<<NBS, 256, 0, stream>>>(ei, cursor, recA);

  // ---- Layer 0: slot exp -> node sums -> fused(att+aggregate) ----
  k_esx0p<<<NBS, 256, 0, stream>>>(recA, s1_0, s2_0, s3_0, esx0);
  k_sums0n<<<NB_SCAN, 256, 0, stream>>>(offs, esx0, sums0);
  k_agg0w<<<(NNODES + 3) / 4, 256, 0, stream>>>(offs, recA, esx0, sums0, proj0,
                                                x, b0, out0b);

  // ---- Layer 1: MFMA GEMM -> slot exp -> sums -> fused(att+aggregate) ----
  k_mm1<<<(NNODES + 63) / 64, 256, 0, stream>>>(out0b, (const short*)B1swz, b1,
                                                proj1, out, s1_1, s2_1, s3_1);
  k_esx1p<<<NBS, 256, 0, stream>>>(recA, s1_1, s2_1, s3_1, es1);
  k_sums1n<<<NB_SCAN, 256, 0, stream>>>(offs, es1, sums1);
  k_agg1<<<(NNODES + 3) / 4, 256, 0, stream>>>(offs, recA, es1, sums1, proj1,
                                               out);
}

// Round 8
// 462.061 us; speedup vs baseline: 1.5773x; 1.0453x over previous
//
#include <hip/hip_runtime.h>
#include <hip/hip_bf16.h>
#include <math.h>

#define NNODES 100000
#define NEDGES 500000
#define NB_SCAN 391  // ceil(NNODES/256)

typedef __attribute__((ext_vector_type(8))) short short8;
typedef __attribute__((ext_vector_type(4))) float f32x4;
typedef __attribute__((ext_vector_type(2))) float f32x2;

__device__ __forceinline__ float bf2f(__hip_bfloat16 v) {
  return __bfloat162float(v);
}
__device__ __forceinline__ unsigned short f2b(float f) {
  __hip_bfloat16 h = __float2bfloat16(f);
  return *(unsigned short*)&h;
}
__device__ __forceinline__ float bits2f_lo(unsigned u) {
  return __uint_as_float(u << 16);
}
__device__ __forceinline__ float bits2f_hi(unsigned u) {
  return __uint_as_float(u & 0xffff0000u);
}

// ================= CSR build ==================================================
__global__ void k_deg(const int* __restrict__ ei, int* __restrict__ deg) {
  const int idx = blockIdx.x * 256 + threadIdx.x;
  if (idx < 2 * NEDGES) atomicAdd(&deg[ei[NEDGES + idx]], 1);
}

__global__ void k_scan1(const int* __restrict__ deg, int* __restrict__ offs,
                        int* __restrict__ bsums) {
  __shared__ int sh[256];
  const int t = threadIdx.x;
  const int i = blockIdx.x * 256 + t;
  const int v = (i < NNODES) ? deg[i] : 0;
  sh[t] = v;
  __syncthreads();
  for (int d = 1; d < 256; d <<= 1) {
    const int add = (t >= d) ? sh[t - d] : 0;
    __syncthreads();
    sh[t] += add;
    __syncthreads();
  }
  if (i < NNODES) offs[i] = sh[t] - v;  // exclusive
  if (t == 255) bsums[blockIdx.x] = sh[255];
}

__global__ void k_scan2(int* __restrict__ bsums) {
  __shared__ int sh[512];
  const int t = threadIdx.x;
  const int v = (t < NB_SCAN) ? bsums[t] : 0;
  sh[t] = v;
  __syncthreads();
  for (int d = 1; d < 512; d <<= 1) {
    const int add = (t >= d) ? sh[t - d] : 0;
    __syncthreads();
    sh[t] += add;
    __syncthreads();
  }
  if (t < NB_SCAN) bsums[t] = sh[t] - v;  // exclusive
}

__global__ void k_scan3(int* __restrict__ offs, const int* __restrict__ bsums,
                        int* __restrict__ cursor) {
  const int i = blockIdx.x * 256 + threadIdx.x;
  if (i < NNODES) {
    const int o = offs[i] + bsums[blockIdx.x];
    offs[i] = o;
    cursor[i] = o;
  }
  if (i == 0) offs[NNODES] = 2 * NEDGES;
}

// Fill slot records: recA=(drug, other|role<<30), rcvA=receiver node.
__global__ void k_fill3(const int* __restrict__ ei, int* __restrict__ cursor,
                        int2* __restrict__ recA, int* __restrict__ rcvA) {
  const int idx = blockIdx.x * 256 + threadIdx.x;
  if (idx >= 2 * NEDGES) return;
  const int n = ei[NEDGES + idx];
  const int e = (idx < NEDGES) ? idx : idx - NEDGES;
  const int drug = ei[e];
  const int other = (idx < NEDGES) ? ei[2 * NEDGES + e] : ei[NEDGES + e];
  const int role = (idx < NEDGES) ? 0 : 1;
  const int pos = atomicAdd(&cursor[n], 1);
  recA[pos] = make_int2(drug, other | (role << 30));
  rcvA[pos] = n;
}

// ========== Fused B-matrix prep: blocks 0..67 -> B0 (layer 0), rest -> B1 =====
__global__ void k_prep(const float* __restrict__ W0, const float* __restrict__ a10,
                       const float* __restrict__ a20, const float* __restrict__ a30,
                       const float* __restrict__ W1, const float* __restrict__ Wsk,
                       const float* __restrict__ a11, const float* __restrict__ a21,
                       const float* __restrict__ a31,
                       __hip_bfloat16* __restrict__ B0,
                       __hip_bfloat16* __restrict__ B1) {
  if (blockIdx.x < 68) {
    const int t = blockIdx.x * 256 + threadIdx.x;  // < 17408
    const int j = t & 7, l = (t >> 3) & 63, s = (t >> 9) & 1, g = t >> 10;
    const int k = s * 32 + ((l >> 4) << 3) + j;
    const int col = g * 16 + (l & 15);
    float v = 0.f;
    if (col < 256) {
      v = W0[col * 64 + k];
    } else if (col < 268) {
      const int idx = col - 256;
      const int r = idx >> 2, h = idx & 3;
      const float* av = (r == 0) ? a10 : (r == 1) ? a20 : a30;
      for (int f = 0; f < 64; ++f)
        v = fmaf(av[h * 64 + f], W0[(h * 64 + f) * 64 + k], v);
    }
    B0[t] = __float2bfloat16(v);
  } else {
    const int t = (blockIdx.x - 68) * 256 + threadIdx.x;  // < 36864
    const int j = t & 7, l = (t >> 3) & 63, s = (t >> 9) & 7, g = t >> 12;
    const int kp = s * 32 + ((l >> 4) << 3) + j;
    const int k = (kp & 3) * 64 + (kp >> 2);  // permuted -> original (head-ilv A)
    const int col = g * 16 + (l & 15);
    float v = 0.f;
    if (col < 64) {
      v = W1[col * 256 + k];
    } else if (col < 128) {
      v = Wsk[(col - 64) * 256 + k];
    } else if (col < 131) {
      const int r = col - 128;
      const float* av = (r == 0) ? a11 : (r == 1) ? a21 : a31;
      for (int f = 0; f < 64; ++f) v = fmaf(av[f], W1[f * 256 + k], v);
    }
    B1[t] = __float2bfloat16(v);
  }
}

// ================= Layer-0 MFMA GEMM: [N,64] x [64,272] =======================
// proj0 stored FP8 e4m3, HEAD-INTERLEAVED: proj0f8[n*256 + f*4 + h] (1B each).
#define LDA0 72
__global__ __launch_bounds__(256) void k_mm0(
    const float* __restrict__ x, const short* __restrict__ B0,
    unsigned char* __restrict__ proj0f8, float* __restrict__ s1,
    float* __restrict__ s2, float* __restrict__ s3) {
  __shared__ __hip_bfloat16 As[64 * LDA0];
  const int t = threadIdx.x;
  const int lane = t & 63, w = t >> 6;
  const int base = blockIdx.x * 64;
  for (int q = 0; q < 4; ++q) {
    const int i = q * 256 + t;
    const int r = i >> 4;
    const int c4 = i & 15;
    int rg = base + r;
    if (rg >= NNODES) rg = NNODES - 1;
    const float4 v = ((const float4*)(x + (size_t)rg * 64))[c4];
    __hip_bfloat16* dst = &As[r * LDA0 + c4 * 4];
    dst[0] = __float2bfloat16(v.x);
    dst[1] = __float2bfloat16(v.y);
    dst[2] = __float2bfloat16(v.z);
    dst[3] = __float2bfloat16(v.w);
  }
  __syncthreads();
  const short8* B8 = (const short8*)B0;
  f32x4 acc[17];
#pragma unroll
  for (int g = 0; g < 17; ++g) acc[g] = (f32x4){0.f, 0.f, 0.f, 0.f};
  const int aoff = (w * 16 + (lane & 15)) * LDA0 + (lane >> 4) * 8;
#pragma unroll
  for (int s = 0; s < 2; ++s) {
    const short8 af = *(const short8*)(&As[aoff + s * 32]);
#pragma unroll
    for (int g = 0; g < 17; ++g) {
      const short8 bf = B8[(g * 2 + s) * 64 + lane];
      acc[g] = __builtin_amdgcn_mfma_f32_16x16x32_bf16(af, bf, acc[g], 0, 0, 0);
    }
  }
  const int r0 = base + w * 16 + (lane >> 4) * 4;
  const int cn = lane & 15;
  // packed fp8 epilogue: heads h of feature f=g*16+cn are acc[g+4h]
#pragma unroll
  for (int g = 0; g < 4; ++g) {
    const int f = g * 16 + cn;
#pragma unroll
    for (int r = 0; r < 4; ++r) {
      const int row = r0 + r;
      if (row < NNODES) {
        unsigned o = __builtin_amdgcn_cvt_pk_fp8_f32(acc[g][r], acc[g + 4][r],
                                                     0u, false);
        o = __builtin_amdgcn_cvt_pk_fp8_f32(acc[g + 8][r], acc[g + 12][r], o,
                                            true);
        *(unsigned*)(proj0f8 + (size_t)row * 256 + f * 4) = o;
      }
    }
  }
#pragma unroll
  for (int r = 0; r < 4; ++r) {
    const int row = r0 + r;
    if (row < NNODES) {
      if (cn < 4) s1[row * 4 + cn] = acc[16][r];
      else if (cn < 8) s2[row * 4 + (cn - 4)] = acc[16][r];
      else if (cn < 12) s3[row * 4 + (cn - 8)] = acc[16][r];
    }
  }
}

// ====== Layer-0 exp-scores, SLOT-PARALLEL (no loops) ==========================
__global__ void k_esx0(const int2* __restrict__ recA, const int* __restrict__ rcvA,
                       const float* __restrict__ s1, const float* __restrict__ s2,
                       const float* __restrict__ s3, float* __restrict__ esx) {
  const int j = blockIdx.x * 256 + threadIdx.x;
  if (j >= 2 * NEDGES) return;
  const int2 rec = recA[j];
  const int n = rcvA[j];
  const int o = rec.y & 0x3FFFFFFF;
  const int role = rec.y >> 30;
  const float4 A = ((const float4*)s1)[rec.x];
  const float4 T = ((const float4*)s2)[role ? o : n];
  const float4 D = ((const float4*)s3)[role ? n : o];
  float4 es;
  float s;
  s = A.x + T.x + D.x; s = s > 0.f ? s : 0.2f * s; es.x = __expf(s);
  s = A.y + T.y + D.y; s = s > 0.f ? s : 0.2f * s; es.y = __expf(s);
  s = A.z + T.z + D.z; s = s > 0.f ? s : 0.2f * s; es.z = __expf(s);
  s = A.w + T.w + D.w; s = s > 0.f ? s : 0.2f * s; es.w = __expf(s);
  ((float4*)esx)[j] = es;
}

// ====== Layer-0 denominator sums: per node, sequential esx reads ==============
__global__ void k_sums0n(const int* __restrict__ offs, const float* __restrict__ esx,
                         float* __restrict__ sums) {
  const int n = blockIdx.x * 256 + threadIdx.x;
  if (n >= NNODES) return;
  const int beg = offs[n], end = offs[n + 1];
  float4 acc = make_float4(0.f, 0.f, 0.f, 0.f);
  for (int j = beg; j < end; ++j) {
    const float4 v = ((const float4*)esx)[j];
    acc.x += v.x; acc.y += v.y; acc.z += v.z; acc.w += v.w;
  }
  ((float4*)sums)[n] = acc;
}

// ====== Layer-0 aggregate, wave/node, FUSED norm, FP8 payload =================
// 32 lanes per slot (uint2 = 8B/lane = 256B row), 2 slots per wave-step;
// half-combine via __shfl_xor(32). att = esx[j]*rcp(sums[n]+sums[o]).
__global__ __launch_bounds__(256) void k_agg0w(
    const int* __restrict__ offs, const int2* __restrict__ recA,
    const float* __restrict__ esx, const float* __restrict__ sums,
    const unsigned char* __restrict__ proj0f8, const float* __restrict__ x,
    const float* __restrict__ b0, __hip_bfloat16* __restrict__ out0b) {
  const int lane = threadIdx.x & 63, wid = threadIdx.x >> 6;
  const int n = blockIdx.x * 4 + wid;
  if (n >= NNODES) return;
  const int beg = offs[n], end = offs[n + 1];
  const int h = lane >> 5;   // which slot of the pair
  const int sl = lane & 31;  // features 2*sl, 2*sl+1 (x 4 heads)
  const float4 sn = ((const float4*)sums)[n];
  float a0 = 0.f, a1 = 0.f, a2 = 0.f, a3 = 0.f;
  float a4 = 0.f, a5 = 0.f, a6 = 0.f, a7 = 0.f;

#define PAIR(J, LIVE)                                                          \
  {                                                                            \
    const int jj = (J) + h;                                                    \
    const bool lv = (LIVE);                                                    \
    const int js = lv ? jj : beg;                                              \
    const int2 rec = recA[js];                                                 \
    const int o = rec.y & 0x3FFFFFFF;                                          \
    const float4 e = ((const float4*)esx)[js];                                 \
    const float4 so = ((const float4*)sums)[o];                                \
    const uint2 r = *(const uint2*)(proj0f8 + (size_t)rec.x * 256 + sl * 8);   \
    const float lm = lv ? 1.f : 0.f;                                           \
    const float t0 = lm * e.x * __builtin_amdgcn_rcpf(sn.x + so.x + 1e-16f);   \
    const float t1 = lm * e.y * __builtin_amdgcn_rcpf(sn.y + so.y + 1e-16f);   \
    const float t2 = lm * e.z * __builtin_amdgcn_rcpf(sn.z + so.z + 1e-16f);   \
    const float t3 = lm * e.w * __builtin_amdgcn_rcpf(sn.w + so.w + 1e-16f);   \
    const f32x2 p01 = __builtin_amdgcn_cvt_pk_f32_fp8(r.x, false);             \
    const f32x2 p23 = __builtin_amdgcn_cvt_pk_f32_fp8(r.x, true);              \
    const f32x2 q01 = __builtin_amdgcn_cvt_pk_f32_fp8(r.y, false);             \
    const f32x2 q23 = __builtin_amdgcn_cvt_pk_f32_fp8(r.y, true);              \
    a0 = fmaf(p01[0], t0, a0);                                                 \
    a1 = fmaf(p01[1], t1, a1);                                                 \
    a2 = fmaf(p23[0], t2, a2);                                                 \
    a3 = fmaf(p23[1], t3, a3);                                                 \
    a4 = fmaf(q01[0], t0, a4);                                                 \
    a5 = fmaf(q01[1], t1, a5);                                                 \
    a6 = fmaf(q23[0], t2, a6);                                                 \
    a7 = fmaf(q23[1], t3, a7);                                                 \
  }

  int j = beg;
  for (; j + 4 <= end; j += 4) {
    PAIR(j, true)
    PAIR(j + 2, true)
  }
  for (; j < end; j += 2) PAIR(j, jj < end)
#undef PAIR

  // combine the two slot-halves
  a0 += __shfl_xor(a0, 32); a1 += __shfl_xor(a1, 32);
  a2 += __shfl_xor(a2, 32); a3 += __shfl_xor(a3, 32);
  a4 += __shfl_xor(a4, 32); a5 += __shfl_xor(a5, 32);
  a6 += __shfl_xor(a6, 32); a7 += __shfl_xor(a7, 32);

  if (h == 0) {
    const float2 xs = ((const float2*)(x + (size_t)n * 64))[sl];
    const int f0 = sl * 2;
    float v0 = a0 + xs.x + b0[f0];
    float v1 = a1 + xs.x + b0[64 + f0];
    float v2 = a2 + xs.x + b0[128 + f0];
    float v3 = a3 + xs.x + b0[192 + f0];
    float v4 = a4 + xs.y + b0[f0 + 1];
    float v5 = a5 + xs.y + b0[64 + f0 + 1];
    float v6 = a6 + xs.y + b0[128 + f0 + 1];
    float v7 = a7 + xs.y + b0[192 + f0 + 1];
    v0 = v0 > 0.f ? v0 : expm1f(v0);
    v1 = v1 > 0.f ? v1 : expm1f(v1);
    v2 = v2 > 0.f ? v2 : expm1f(v2);
    v3 = v3 > 0.f ? v3 : expm1f(v3);
    v4 = v4 > 0.f ? v4 : expm1f(v4);
    v5 = v5 > 0.f ? v5 : expm1f(v5);
    v6 = v6 > 0.f ? v6 : expm1f(v6);
    v7 = v7 > 0.f ? v7 : expm1f(v7);
    uint4 o;
    o.x = (unsigned)f2b(v0) | ((unsigned)f2b(v1) << 16);
    o.y = (unsigned)f2b(v2) | ((unsigned)f2b(v3) << 16);
    o.z = (unsigned)f2b(v4) | ((unsigned)f2b(v5) << 16);
    o.w = (unsigned)f2b(v6) | ((unsigned)f2b(v7) << 16);
    *(uint4*)(out0b + (size_t)n * 256 + sl * 8) = o;
  }
}

// ====== Layer-1 MFMA GEMM: [N,256] x [256,144] (k-permuted B) =================
#define LDA1 264
__global__ __launch_bounds__(256) void k_mm1(
    const __hip_bfloat16* __restrict__ hsrc, const short* __restrict__ B1,
    const float* __restrict__ b1, __hip_bfloat16* __restrict__ proj1,
    float* __restrict__ out, float* __restrict__ s1, float* __restrict__ s2,
    float* __restrict__ s3) {
  __shared__ short As[64 * LDA1];
  const int t = threadIdx.x;
  const int lane = t & 63, w = t >> 6;
  const int base = blockIdx.x * 64;
  for (int q = 0; q < 8; ++q) {
    const int i = q * 256 + t;
    const int r = i >> 5;
    const int c = (i & 31) * 8;
    int rg = base + r;
    if (rg >= NNODES) rg = NNODES - 1;
    const float4 v = *(const float4*)((const short*)hsrc + (size_t)rg * 256 + c);
    *(float4*)(&As[r * LDA1 + c]) = v;
  }
  __syncthreads();
  const short8* B8 = (const short8*)B1;
  f32x4 acc[9];
#pragma unroll
  for (int g = 0; g < 9; ++g) acc[g] = (f32x4){0.f, 0.f, 0.f, 0.f};
  const int aoff = (w * 16 + (lane & 15)) * LDA1 + (lane >> 4) * 8;
#pragma unroll
  for (int s = 0; s < 8; ++s) {
    const short8 af = *(const short8*)(&As[aoff + s * 32]);
#pragma unroll
    for (int g = 0; g < 9; ++g) {
      const short8 bf = B8[(g * 8 + s) * 64 + lane];
      acc[g] = __builtin_amdgcn_mfma_f32_16x16x32_bf16(af, bf, acc[g], 0, 0, 0);
    }
  }
  const int r0 = base + w * 16 + (lane >> 4) * 4;
  const int cn = lane & 15;
#pragma unroll
  for (int g = 0; g < 4; ++g) {
    const int col = g * 16 + cn;
#pragma unroll
    for (int r = 0; r < 4; ++r) {
      const int row = r0 + r;
      if (row < NNODES)
        proj1[(size_t)row * 64 + col] = __float2bfloat16(acc[g][r]);
    }
  }
#pragma unroll
  for (int g = 4; g < 8; ++g) {
    const int col = (g - 4) * 16 + cn;
    const float bv = b1[col];
#pragma unroll
    for (int r = 0; r < 4; ++r) {
      const int row = r0 + r;
      if (row < NNODES) out[(size_t)row * 64 + col] = acc[g][r] + bv;
    }
  }
#pragma unroll
  for (int r = 0; r < 4; ++r) {
    const int row = r0 + r;
    if (row < NNODES) {
      if (cn == 0) s1[row] = acc[8][r];
      else if (cn == 1) s2[row] = acc[8][r];
      else if (cn == 2) s3[row] = acc[8][r];
    }
  }
}

// ====== Layer-1 exp-scores, SLOT-PARALLEL =====================================
__global__ void k_esx1(const int2* __restrict__ recA, const int* __restrict__ rcvA,
                       const float* __restrict__ s1, const float* __restrict__ s2,
                       const float* __restrict__ s3, float* __restrict__ es1) {
  const int j = blockIdx.x * 256 + threadIdx.x;
  if (j >= 2 * NEDGES) return;
  const int2 rec = recA[j];
  const int n = rcvA[j];
  const int o = rec.y & 0x3FFFFFFF;
  const int role = rec.y >> 30;
  float s = s1[rec.x] + s2[role ? o : n] + s3[role ? n : o];
  s = s > 0.f ? s : 0.2f * s;
  es1[j] = __expf(s);
}

// ====== Layer-1 denominator sums: per node, sequential ========================
__global__ void k_sums1n(const int* __restrict__ offs, const float* __restrict__ es1,
                         float* __restrict__ sums) {
  const int n = blockIdx.x * 256 + threadIdx.x;
  if (n >= NNODES) return;
  const int beg = offs[n], end = offs[n + 1];
  float acc = 0.f;
  for (int j = beg; j < end; ++j) acc += es1[j];
  sums[n] = acc;
}

// ========== Layer-1 aggregate, wave/node, FUSED normalization =================
// 8 lanes per slot (uint4 = 16B/lane), 8 slots per wave-step; group-combine via
// __shfl_xor butterfly (8,16,32).
__global__ __launch_bounds__(256) void k_agg1(
    const int* __restrict__ offs, const int2* __restrict__ recA,
    const float* __restrict__ es1, const float* __restrict__ sums,
    const __hip_bfloat16* __restrict__ proj1, float* __restrict__ dout) {
  const int lane = threadIdx.x & 63, wid = threadIdx.x >> 6;
  const int n = blockIdx.x * 4 + wid;
  if (n >= NNODES) return;
  const int beg = offs[n], end = offs[n + 1];
  if (beg == end) return;  // dout row already holds skip+bias from k_mm1
  const int g = lane >> 3;  // slot group 0..7
  const int li = lane & 7;  // features li*8 .. li*8+7
  const float sn = sums[n];
  float a0 = 0.f, a1 = 0.f, a2 = 0.f, a3 = 0.f;
  float a4 = 0.f, a5 = 0.f, a6 = 0.f, a7 = 0.f;

#define SLOT(J, LIVE)                                                          \
  {                                                                            \
    const int jj = (J) + g;                                                    \
    const bool lv = (LIVE);                                                    \
    const int js = lv ? jj : beg;                                              \
    const int2 rec = recA[js];                                                 \
    const int o = rec.y & 0x3FFFFFFF;                                          \
    const float e = es1[js];                                                   \
    const float t =                                                            \
        (lv ? e : 0.f) * __builtin_amdgcn_rcpf(sn + sums[o] + 1e-16f);         \
    const uint4 r = *(const uint4*)(proj1 + (size_t)rec.x * 64 + li * 8);      \
    a0 = fmaf(bits2f_lo(r.x), t, a0);                                          \
    a1 = fmaf(bits2f_hi(r.x), t, a1);                                          \
    a2 = fmaf(bits2f_lo(r.y), t, a2);                                          \
    a3 = fmaf(bits2f_hi(r.y), t, a3);                                          \
    a4 = fmaf(bits2f_lo(r.z), t, a4);                                          \
    a5 = fmaf(bits2f_hi(r.z), t, a5);                                          \
    a6 = fmaf(bits2f_lo(r.w), t, a6);                                          \
    a7 = fmaf(bits2f_hi(r.w), t, a7);                                          \
  }

  int j = beg;
  for (; j + 8 <= end; j += 8) SLOT(j, true)
  for (; j < end; j += 8) SLOT(j, jj < end)
#undef SLOT

  // butterfly-reduce across the 8 slot groups
#define RED(m)                                                                 \
  a0 += __shfl_xor(a0, m); a1 += __shfl_xor(a1, m);                            \
  a2 += __shfl_xor(a2, m); a3 += __shfl_xor(a3, m);                            \
  a4 += __shfl_xor(a4, m); a5 += __shfl_xor(a5, m);                            \
  a6 += __shfl_xor(a6, m); a7 += __shfl_xor(a7, m);
  RED(8) RED(16) RED(32)
#undef RED

  if (g == 0) {
    float4* dp = (float4*)(dout + (size_t)n * 64 + li * 8);
    float4 d0 = dp[0], d1 = dp[1];
    d0.x += a0; d0.y += a1; d0.z += a2; d0.w += a3;
    d1.x += a4; d1.y += a5; d1.z += a6; d1.w += a7;
    dp[0] = d0;
    dp[1] = d1;
  }
}

extern "C" void kernel_launch(void* const* d_in, const int* in_sizes, int n_in,
                              void* d_out, int out_size, void* d_ws, size_t ws_size,
                              hipStream_t stream) {
  const float* x = (const float*)d_in[0];
  const int* ei = (const int*)d_in[1];
  const float* W0 = (const float*)d_in[2];
  const float* a10 = (const float*)d_in[3];
  const float* a20 = (const float*)d_in[4];
  const float* a30 = (const float*)d_in[5];
  // d_in[6] = Wskip0: unused (layer-0 skip is identity, F==DIN)
  const float* b0 = (const float*)d_in[7];
  const float* W1 = (const float*)d_in[8];
  const float* a11 = (const float*)d_in[9];
  const float* a21 = (const float*)d_in[10];
  const float* a31 = (const float*)d_in[11];
  const float* Wskip1 = (const float*)d_in[12];
  const float* b1 = (const float*)d_in[13];
  float* out = (float*)d_out;

  // ---- Workspace layout (region sizes unchanged from R1; proj0 now fp8) ----
  unsigned char* proj0f8 = (unsigned char*)d_ws;       // N*256 B (fp8 head-ilv)
  __hip_bfloat16* out0b =
      (__hip_bfloat16*)d_ws + (size_t)NNODES * 256;    // N*256 bf16 (head-ilv)
  float* s1_0 = (float*)(out0b + (size_t)NNODES * 256);  // N*4 x3
  float* s2_0 = s1_0 + (size_t)NNODES * 4;
  float* s3_0 = s2_0 + (size_t)NNODES * 4;
  float* sums0 = s3_0 + (size_t)NNODES * 4;            // N*4
  float* esx0 = sums0 + (size_t)NNODES * 4;            // 2E*4
  int2* recA = (int2*)(esx0 + (size_t)2 * NEDGES * 4); // 2E int2
  int* rcvA = (int*)(recA + 2 * NEDGES);               // 2E
  int* offs = rcvA + 2 * NEDGES;                       // N+16
  float* s1_1 = (float*)(offs + NNODES + 16);          // N x3
  float* s2_1 = s1_1 + NNODES;
  float* s3_1 = s2_1 + NNODES;
  float* sums1 = s3_1 + NNODES;                        // N
  __hip_bfloat16* B0swz = (__hip_bfloat16*)(sums1 + NNODES);  // 17408 bf16
  __hip_bfloat16* B1swz = B0swz + 17408;               // 36864 bf16
  // CSR-build int scratch aliases esx0 (dead until k_esx0):
  int* deg = (int*)esx0;
  int* cursor = deg + NNODES;
  int* bsums = cursor + NNODES;

  __hip_bfloat16* proj1 = (__hip_bfloat16*)d_ws;  // reuse proj0 region (bf16)
  float* es1 = esx0;              // layer-1 exp/att slots (esx0 dead after agg0w)

  // ---- fused weight prep ----
  k_prep<<<212, 256, 0, stream>>>(W0, a10, a20, a30, W1, Wskip1, a11, a21, a31,
                                  B0swz, B1swz);

  // ---- Layer-0 projection + scores via MFMA (fp8 proj0) ----
  k_mm0<<<(NNODES + 63) / 64, 256, 0, stream>>>(x, (const short*)B0swz, proj0f8,
                                                s1_0, s2_0, s3_0);

  // ---- CSR build ----
  hipMemsetAsync(deg, 0, NNODES * sizeof(int), stream);
  k_deg<<<(2 * NEDGES + 255) / 256, 256, 0, stream>>>(ei, deg);
  k_scan1<<<NB_SCAN, 256, 0, stream>>>(deg, offs, bsums);
  k_scan2<<<1, 512, 0, stream>>>(bsums);
  k_scan3<<<NB_SCAN, 256, 0, stream>>>(offs, bsums, cursor);
  k_fill3<<<(2 * NEDGES + 255) / 256, 256, 0, stream>>>(ei, cursor, recA, rcvA);

  // ---- Layer 0: slot exp -> node sums -> fused(att+aggregate, fp8) ----
  const int NBS = (2 * NEDGES + 255) / 256;
  k_esx0<<<NBS, 256, 0, stream>>>(recA, rcvA, s1_0, s2_0, s3_0, esx0);
  k_sums0n<<<NB_SCAN, 256, 0, stream>>>(offs, esx0, sums0);
  k_agg0w<<<(NNODES + 3) / 4, 256, 0, stream>>>(offs, recA, esx0, sums0,
                                                proj0f8, x, b0, out0b);

  // ---- Layer 1: MFMA GEMM -> slot exp -> sums -> fused(att+aggregate) ----
  k_mm1<<<(NNODES + 63) / 64, 256, 0, stream>>>(out0b, (const short*)B1swz, b1,
                                                proj1, out, s1_1, s2_1, s3_1);
  k_esx1<<<NBS, 256, 0, stream>>>(recA, rcvA, s1_1, s2_1, s3_1, es1);
  k_sums1n<<<NB_SCAN, 256, 0, stream>>>(offs, es1, sums1);
  k_agg1<<<(NNODES + 3) / 4, 256, 0, stream>>>(offs, recA, es1, sums1, proj1,
                                               out);
}

// Round 9
// 454.062 us; speedup vs baseline: 1.6051x; 1.0176x over previous
//
#include <hip/hip_runtime.h>
#include <hip/hip_bf16.h>
#include <math.h>

#define NNODES 100000
#define NEDGES 500000
#define NB_SCAN 391  // ceil(NNODES/256)

typedef __attribute__((ext_vector_type(8))) short short8;
typedef __attribute__((ext_vector_type(4))) float f32x4;
typedef __attribute__((ext_vector_type(2))) float f32x2;

__device__ __forceinline__ float bf2f(__hip_bfloat16 v) {
  return __bfloat162float(v);
}
__device__ __forceinline__ unsigned short f2b(float f) {
  __hip_bfloat16 h = __float2bfloat16(f);
  return *(unsigned short*)&h;
}
__device__ __forceinline__ float bits2f_lo(unsigned u) {
  return __uint_as_float(u << 16);
}
__device__ __forceinline__ float bits2f_hi(unsigned u) {
  return __uint_as_float(u & 0xffff0000u);
}

// ================= CSR build ==================================================
__global__ void k_deg(const int* __restrict__ ei, int* __restrict__ deg) {
  const int idx = blockIdx.x * 256 + threadIdx.x;
  if (idx < 2 * NEDGES) atomicAdd(&deg[ei[NEDGES + idx]], 1);
}

__global__ void k_scan1(const int* __restrict__ deg, int* __restrict__ offs,
                        int* __restrict__ bsums) {
  __shared__ int sh[256];
  const int t = threadIdx.x;
  const int i = blockIdx.x * 256 + t;
  const int v = (i < NNODES) ? deg[i] : 0;
  sh[t] = v;
  __syncthreads();
  for (int d = 1; d < 256; d <<= 1) {
    const int add = (t >= d) ? sh[t - d] : 0;
    __syncthreads();
    sh[t] += add;
    __syncthreads();
  }
  if (i < NNODES) offs[i] = sh[t] - v;  // exclusive
  if (t == 255) bsums[blockIdx.x] = sh[255];
}

__global__ void k_scan2(int* __restrict__ bsums) {
  __shared__ int sh[512];
  const int t = threadIdx.x;
  const int v = (t < NB_SCAN) ? bsums[t] : 0;
  sh[t] = v;
  __syncthreads();
  for (int d = 1; d < 512; d <<= 1) {
    const int add = (t >= d) ? sh[t - d] : 0;
    __syncthreads();
    sh[t] += add;
    __syncthreads();
  }
  if (t < NB_SCAN) bsums[t] = sh[t] - v;  // exclusive
}

__global__ void k_scan3(int* __restrict__ offs, const int* __restrict__ bsums,
                        int* __restrict__ cursor) {
  const int i = blockIdx.x * 256 + threadIdx.x;
  if (i < NNODES) {
    const int o = offs[i] + bsums[blockIdx.x];
    offs[i] = o;
    cursor[i] = o;
  }
  if (i == 0) offs[NNODES] = 2 * NEDGES;
}

// Fill slot records: recA=(drug, other|role<<30), rcvA=receiver node.
__global__ void k_fill3(const int* __restrict__ ei, int* __restrict__ cursor,
                        int2* __restrict__ recA, int* __restrict__ rcvA) {
  const int idx = blockIdx.x * 256 + threadIdx.x;
  if (idx >= 2 * NEDGES) return;
  const int n = ei[NEDGES + idx];
  const int e = (idx < NEDGES) ? idx : idx - NEDGES;
  const int drug = ei[e];
  const int other = (idx < NEDGES) ? ei[2 * NEDGES + e] : ei[NEDGES + e];
  const int role = (idx < NEDGES) ? 0 : 1;
  const int pos = atomicAdd(&cursor[n], 1);
  recA[pos] = make_int2(drug, other | (role << 30));
  rcvA[pos] = n;
}

// ========== Fused B-matrix prep: blocks 0..67 -> B0 (layer 0), rest -> B1 =====
__global__ void k_prep(const float* __restrict__ W0, const float* __restrict__ a10,
                       const float* __restrict__ a20, const float* __restrict__ a30,
                       const float* __restrict__ W1, const float* __restrict__ Wsk,
                       const float* __restrict__ a11, const float* __restrict__ a21,
                       const float* __restrict__ a31,
                       __hip_bfloat16* __restrict__ B0,
                       __hip_bfloat16* __restrict__ B1) {
  if (blockIdx.x < 68) {
    const int t = blockIdx.x * 256 + threadIdx.x;  // < 17408
    const int j = t & 7, l = (t >> 3) & 63, s = (t >> 9) & 1, g = t >> 10;
    const int k = s * 32 + ((l >> 4) << 3) + j;
    const int col = g * 16 + (l & 15);
    float v = 0.f;
    if (col < 256) {
      v = W0[col * 64 + k];
    } else if (col < 268) {
      const int idx = col - 256;
      const int r = idx >> 2, h = idx & 3;
      const float* av = (r == 0) ? a10 : (r == 1) ? a20 : a30;
      for (int f = 0; f < 64; ++f)
        v = fmaf(av[h * 64 + f], W0[(h * 64 + f) * 64 + k], v);
    }
    B0[t] = __float2bfloat16(v);
  } else {
    const int t = (blockIdx.x - 68) * 256 + threadIdx.x;  // < 36864
    const int j = t & 7, l = (t >> 3) & 63, s = (t >> 9) & 7, g = t >> 12;
    const int kp = s * 32 + ((l >> 4) << 3) + j;
    const int k = (kp & 3) * 64 + (kp >> 2);  // permuted -> original (head-ilv A)
    const int col = g * 16 + (l & 15);
    float v = 0.f;
    if (col < 64) {
      v = W1[col * 256 + k];
    } else if (col < 128) {
      v = Wsk[(col - 64) * 256 + k];
    } else if (col < 131) {
      const int r = col - 128;
      const float* av = (r == 0) ? a11 : (r == 1) ? a21 : a31;
      for (int f = 0; f < 64; ++f) v = fmaf(av[f], W1[f * 256 + k], v);
    }
    B1[t] = __float2bfloat16(v);
  }
}

// ================= Layer-0 MFMA GEMM: [N,64] x [64,272] =======================
// proj0 stored FP8 e4m3, HEAD-INTERLEAVED: proj0f8[n*256 + f*4 + h] (1B each).
#define LDA0 72
__global__ __launch_bounds__(256) void k_mm0(
    const float* __restrict__ x, const short* __restrict__ B0,
    unsigned char* __restrict__ proj0f8, float* __restrict__ s1,
    float* __restrict__ s2, float* __restrict__ s3) {
  __shared__ __hip_bfloat16 As[64 * LDA0];
  const int t = threadIdx.x;
  const int lane = t & 63, w = t >> 6;
  const int base = blockIdx.x * 64;
  for (int q = 0; q < 4; ++q) {
    const int i = q * 256 + t;
    const int r = i >> 4;
    const int c4 = i & 15;
    int rg = base + r;
    if (rg >= NNODES) rg = NNODES - 1;
    const float4 v = ((const float4*)(x + (size_t)rg * 64))[c4];
    __hip_bfloat16* dst = &As[r * LDA0 + c4 * 4];
    dst[0] = __float2bfloat16(v.x);
    dst[1] = __float2bfloat16(v.y);
    dst[2] = __float2bfloat16(v.z);
    dst[3] = __float2bfloat16(v.w);
  }
  __syncthreads();
  const short8* B8 = (const short8*)B0;
  f32x4 acc[17];
#pragma unroll
  for (int g = 0; g < 17; ++g) acc[g] = (f32x4){0.f, 0.f, 0.f, 0.f};
  const int aoff = (w * 16 + (lane & 15)) * LDA0 + (lane >> 4) * 8;
#pragma unroll
  for (int s = 0; s < 2; ++s) {
    const short8 af = *(const short8*)(&As[aoff + s * 32]);
#pragma unroll
    for (int g = 0; g < 17; ++g) {
      const short8 bf = B8[(g * 2 + s) * 64 + lane];
      acc[g] = __builtin_amdgcn_mfma_f32_16x16x32_bf16(af, bf, acc[g], 0, 0, 0);
    }
  }
  const int r0 = base + w * 16 + (lane >> 4) * 4;
  const int cn = lane & 15;
  // packed fp8 epilogue: heads h of feature f=g*16+cn are acc[g+4h]
#pragma unroll
  for (int g = 0; g < 4; ++g) {
    const int f = g * 16 + cn;
#pragma unroll
    for (int r = 0; r < 4; ++r) {
      const int row = r0 + r;
      if (row < NNODES) {
        unsigned o = __builtin_amdgcn_cvt_pk_fp8_f32(acc[g][r], acc[g + 4][r],
                                                     0u, false);
        o = __builtin_amdgcn_cvt_pk_fp8_f32(acc[g + 8][r], acc[g + 12][r], o,
                                            true);
        *(unsigned*)(proj0f8 + (size_t)row * 256 + f * 4) = o;
      }
    }
  }
#pragma unroll
  for (int r = 0; r < 4; ++r) {
    const int row = r0 + r;
    if (row < NNODES) {
      if (cn < 4) s1[row * 4 + cn] = acc[16][r];
      else if (cn < 8) s2[row * 4 + (cn - 4)] = acc[16][r];
      else if (cn < 12) s3[row * 4 + (cn - 8)] = acc[16][r];
    }
  }
}

// ====== Layer-0 exp-scores, SLOT-PARALLEL (no loops) ==========================
__global__ void k_esx0(const int2* __restrict__ recA, const int* __restrict__ rcvA,
                       const float* __restrict__ s1, const float* __restrict__ s2,
                       const float* __restrict__ s3, float* __restrict__ esx) {
  const int j = blockIdx.x * 256 + threadIdx.x;
  if (j >= 2 * NEDGES) return;
  const int2 rec = recA[j];
  const int n = rcvA[j];
  const int o = rec.y & 0x3FFFFFFF;
  const int role = rec.y >> 30;
  const float4 A = ((const float4*)s1)[rec.x];
  const float4 T = ((const float4*)s2)[role ? o : n];
  const float4 D = ((const float4*)s3)[role ? n : o];
  float4 es;
  float s;
  s = A.x + T.x + D.x; s = s > 0.f ? s : 0.2f * s; es.x = __expf(s);
  s = A.y + T.y + D.y; s = s > 0.f ? s : 0.2f * s; es.y = __expf(s);
  s = A.z + T.z + D.z; s = s > 0.f ? s : 0.2f * s; es.z = __expf(s);
  s = A.w + T.w + D.w; s = s > 0.f ? s : 0.2f * s; es.w = __expf(s);
  ((float4*)esx)[j] = es;
}

// ====== Layer-0 denominator sums: per node, sequential esx reads ==============
__global__ void k_sums0n(const int* __restrict__ offs, const float* __restrict__ esx,
                         float* __restrict__ sums) {
  const int n = blockIdx.x * 256 + threadIdx.x;
  if (n >= NNODES) return;
  const int beg = offs[n], end = offs[n + 1];
  float4 acc = make_float4(0.f, 0.f, 0.f, 0.f);
  for (int j = beg; j < end; ++j) {
    const float4 v = ((const float4*)esx)[j];
    acc.x += v.x; acc.y += v.y; acc.z += v.z; acc.w += v.w;
  }
  ((float4*)sums)[n] = acc;
}

// ====== Layer-0 aggregate, wave/node, FUSED norm, FP8, 4 slots/step ===========
// 16 lanes per slot (uint4 = 16B/lane = 256B row), 4 slots per wave-step;
// group-combine via __shfl_xor(16,32). att = esx[j]*rcp(sums[n]+sums[o]).
__global__ __launch_bounds__(256) void k_agg0w(
    const int* __restrict__ offs, const int2* __restrict__ recA,
    const float* __restrict__ esx, const float* __restrict__ sums,
    const unsigned char* __restrict__ proj0f8, const float* __restrict__ x,
    const float* __restrict__ b0, __hip_bfloat16* __restrict__ out0b) {
  const int lane = threadIdx.x & 63, wid = threadIdx.x >> 6;
  const int n = blockIdx.x * 4 + wid;
  if (n >= NNODES) return;
  const int beg = offs[n], end = offs[n + 1];
  const int g = lane >> 4;   // slot group 0..3
  const int li = lane & 15;  // 16B chunk: row bytes li*16 .. li*16+15
  const float4 sn = ((const float4*)sums)[n];
  // acc: word w (feature li*4+w), component = head 0..3
  f32x4 a0 = (f32x4){0.f, 0.f, 0.f, 0.f};
  f32x4 a1 = (f32x4){0.f, 0.f, 0.f, 0.f};
  f32x4 a2 = (f32x4){0.f, 0.f, 0.f, 0.f};
  f32x4 a3 = (f32x4){0.f, 0.f, 0.f, 0.f};

#define STEP(J, LIVE)                                                          \
  {                                                                            \
    const int jj = (J) + g;                                                    \
    const bool lv = (LIVE);                                                    \
    const int js = lv ? jj : beg;                                              \
    const int2 rec = recA[js];                                                 \
    const int o = rec.y & 0x3FFFFFFF;                                          \
    const float4 e = ((const float4*)esx)[js];                                 \
    const float4 so = ((const float4*)sums)[o];                                \
    const uint4 r = *(const uint4*)(proj0f8 + (size_t)rec.x * 256 + li * 16);  \
    const float lm = lv ? 1.f : 0.f;                                           \
    const float t0 = lm * e.x * __builtin_amdgcn_rcpf(sn.x + so.x + 1e-16f);   \
    const float t1 = lm * e.y * __builtin_amdgcn_rcpf(sn.y + so.y + 1e-16f);   \
    const float t2 = lm * e.z * __builtin_amdgcn_rcpf(sn.z + so.z + 1e-16f);   \
    const float t3 = lm * e.w * __builtin_amdgcn_rcpf(sn.w + so.w + 1e-16f);   \
    f32x2 c;                                                                   \
    c = __builtin_amdgcn_cvt_pk_f32_fp8(r.x, false);                           \
    a0[0] = fmaf(c[0], t0, a0[0]); a0[1] = fmaf(c[1], t1, a0[1]);              \
    c = __builtin_amdgcn_cvt_pk_f32_fp8(r.x, true);                            \
    a0[2] = fmaf(c[0], t2, a0[2]); a0[3] = fmaf(c[1], t3, a0[3]);              \
    c = __builtin_amdgcn_cvt_pk_f32_fp8(r.y, false);                           \
    a1[0] = fmaf(c[0], t0, a1[0]); a1[1] = fmaf(c[1], t1, a1[1]);              \
    c = __builtin_amdgcn_cvt_pk_f32_fp8(r.y, true);                            \
    a1[2] = fmaf(c[0], t2, a1[2]); a1[3] = fmaf(c[1], t3, a1[3]);              \
    c = __builtin_amdgcn_cvt_pk_f32_fp8(r.z, false);                           \
    a2[0] = fmaf(c[0], t0, a2[0]); a2[1] = fmaf(c[1], t1, a2[1]);              \
    c = __builtin_amdgcn_cvt_pk_f32_fp8(r.z, true);                            \
    a2[2] = fmaf(c[0], t2, a2[2]); a2[3] = fmaf(c[1], t3, a2[3]);              \
    c = __builtin_amdgcn_cvt_pk_f32_fp8(r.w, false);                           \
    a3[0] = fmaf(c[0], t0, a3[0]); a3[1] = fmaf(c[1], t1, a3[1]);              \
    c = __builtin_amdgcn_cvt_pk_f32_fp8(r.w, true);                            \
    a3[2] = fmaf(c[0], t2, a3[2]); a3[3] = fmaf(c[1], t3, a3[3]);              \
  }

  int j = beg;
  for (; j + 8 <= end; j += 8) {
    STEP(j, true)
    STEP(j + 4, true)
  }
  for (; j < end; j += 4) STEP(j, jj < end)
#undef STEP

  // combine the four slot-groups
#define RED(m)                                                                 \
  a0[0] += __shfl_xor(a0[0], m); a0[1] += __shfl_xor(a0[1], m);                \
  a0[2] += __shfl_xor(a0[2], m); a0[3] += __shfl_xor(a0[3], m);                \
  a1[0] += __shfl_xor(a1[0], m); a1[1] += __shfl_xor(a1[1], m);                \
  a1[2] += __shfl_xor(a1[2], m); a1[3] += __shfl_xor(a1[3], m);                \
  a2[0] += __shfl_xor(a2[0], m); a2[1] += __shfl_xor(a2[1], m);                \
  a2[2] += __shfl_xor(a2[2], m); a2[3] += __shfl_xor(a2[3], m);                \
  a3[0] += __shfl_xor(a3[0], m); a3[1] += __shfl_xor(a3[1], m);                \
  a3[2] += __shfl_xor(a3[2], m); a3[3] += __shfl_xor(a3[3], m);
  RED(16) RED(32)
#undef RED

  if (g == 0) {
    const float4 xv = *(const float4*)(x + (size_t)n * 64 + li * 4);
    const float4 bh0 = *(const float4*)(b0 + li * 4);
    const float4 bh1 = *(const float4*)(b0 + 64 + li * 4);
    const float4 bh2 = *(const float4*)(b0 + 128 + li * 4);
    const float4 bh3 = *(const float4*)(b0 + 192 + li * 4);
#define EL(v_) ((v_) > 0.f ? (v_) : expm1f(v_))
    const float w00 = EL(a0[0] + xv.x + bh0.x);
    const float w01 = EL(a0[1] + xv.x + bh1.x);
    const float w02 = EL(a0[2] + xv.x + bh2.x);
    const float w03 = EL(a0[3] + xv.x + bh3.x);
    const float w10 = EL(a1[0] + xv.y + bh0.y);
    const float w11 = EL(a1[1] + xv.y + bh1.y);
    const float w12 = EL(a1[2] + xv.y + bh2.y);
    const float w13 = EL(a1[3] + xv.y + bh3.y);
    const float w20 = EL(a2[0] + xv.z + bh0.z);
    const float w21 = EL(a2[1] + xv.z + bh1.z);
    const float w22 = EL(a2[2] + xv.z + bh2.z);
    const float w23 = EL(a2[3] + xv.z + bh3.z);
    const float w30 = EL(a3[0] + xv.w + bh0.w);
    const float w31 = EL(a3[1] + xv.w + bh1.w);
    const float w32 = EL(a3[2] + xv.w + bh2.w);
    const float w33 = EL(a3[3] + xv.w + bh3.w);
#undef EL
    uint4 o0, o1;
    o0.x = (unsigned)f2b(w00) | ((unsigned)f2b(w01) << 16);
    o0.y = (unsigned)f2b(w02) | ((unsigned)f2b(w03) << 16);
    o0.z = (unsigned)f2b(w10) | ((unsigned)f2b(w11) << 16);
    o0.w = (unsigned)f2b(w12) | ((unsigned)f2b(w13) << 16);
    o1.x = (unsigned)f2b(w20) | ((unsigned)f2b(w21) << 16);
    o1.y = (unsigned)f2b(w22) | ((unsigned)f2b(w23) << 16);
    o1.z = (unsigned)f2b(w30) | ((unsigned)f2b(w31) << 16);
    o1.w = (unsigned)f2b(w32) | ((unsigned)f2b(w33) << 16);
    *(uint4*)(out0b + (size_t)n * 256 + li * 16) = o0;
    *(uint4*)(out0b + (size_t)n * 256 + li * 16 + 8) = o1;
  }
}

// ====== Layer-1 MFMA GEMM: [N,256] x [256,144] (k-permuted B) =================
#define LDA1 264
__global__ __launch_bounds__(256) void k_mm1(
    const __hip_bfloat16* __restrict__ hsrc, const short* __restrict__ B1,
    const float* __restrict__ b1, __hip_bfloat16* __restrict__ proj1,
    float* __restrict__ out, float* __restrict__ s1, float* __restrict__ s2,
    float* __restrict__ s3) {
  __shared__ short As[64 * LDA1];
  const int t = threadIdx.x;
  const int lane = t & 63, w = t >> 6;
  const int base = blockIdx.x * 64;
  for (int q = 0; q < 8; ++q) {
    const int i = q * 256 + t;
    const int r = i >> 5;
    const int c = (i & 31) * 8;
    int rg = base + r;
    if (rg >= NNODES) rg = NNODES - 1;
    const float4 v = *(const float4*)((const short*)hsrc + (size_t)rg * 256 + c);
    *(float4*)(&As[r * LDA1 + c]) = v;
  }
  __syncthreads();
  const short8* B8 = (const short8*)B1;
  f32x4 acc[9];
#pragma unroll
  for (int g = 0; g < 9; ++g) acc[g] = (f32x4){0.f, 0.f, 0.f, 0.f};
  const int aoff = (w * 16 + (lane & 15)) * LDA1 + (lane >> 4) * 8;
#pragma unroll
  for (int s = 0; s < 8; ++s) {
    const short8 af = *(const short8*)(&As[aoff + s * 32]);
#pragma unroll
    for (int g = 0; g < 9; ++g) {
      const short8 bf = B8[(g * 8 + s) * 64 + lane];
      acc[g] = __builtin_amdgcn_mfma_f32_16x16x32_bf16(af, bf, acc[g], 0, 0, 0);
    }
  }
  const int r0 = base + w * 16 + (lane >> 4) * 4;
  const int cn = lane & 15;
#pragma unroll
  for (int g = 0; g < 4; ++g) {
    const int col = g * 16 + cn;
#pragma unroll
    for (int r = 0; r < 4; ++r) {
      const int row = r0 + r;
      if (row < NNODES)
        proj1[(size_t)row * 64 + col] = __float2bfloat16(acc[g][r]);
    }
  }
#pragma unroll
  for (int g = 4; g < 8; ++g) {
    const int col = (g - 4) * 16 + cn;
    const float bv = b1[col];
#pragma unroll
    for (int r = 0; r < 4; ++r) {
      const int row = r0 + r;
      if (row < NNODES) out[(size_t)row * 64 + col] = acc[g][r] + bv;
    }
  }
#pragma unroll
  for (int r = 0; r < 4; ++r) {
    const int row = r0 + r;
    if (row < NNODES) {
      if (cn == 0) s1[row] = acc[8][r];
      else if (cn == 1) s2[row] = acc[8][r];
      else if (cn == 2) s3[row] = acc[8][r];
    }
  }
}

// ====== Layer-1 exp-scores, SLOT-PARALLEL =====================================
__global__ void k_esx1(const int2* __restrict__ recA, const int* __restrict__ rcvA,
                       const float* __restrict__ s1, const float* __restrict__ s2,
                       const float* __restrict__ s3, float* __restrict__ es1) {
  const int j = blockIdx.x * 256 + threadIdx.x;
  if (j >= 2 * NEDGES) return;
  const int2 rec = recA[j];
  const int n = rcvA[j];
  const int o = rec.y & 0x3FFFFFFF;
  const int role = rec.y >> 30;
  float s = s1[rec.x] + s2[role ? o : n] + s3[role ? n : o];
  s = s > 0.f ? s : 0.2f * s;
  es1[j] = __expf(s);
}

// ====== Layer-1 denominator sums: per node, sequential ========================
__global__ void k_sums1n(const int* __restrict__ offs, const float* __restrict__ es1,
                         float* __restrict__ sums) {
  const int n = blockIdx.x * 256 + threadIdx.x;
  if (n >= NNODES) return;
  const int beg = offs[n], end = offs[n + 1];
  float acc = 0.f;
  for (int j = beg; j < end; ++j) acc += es1[j];
  sums[n] = acc;
}

// ========== Layer-1 aggregate, wave/node, FUSED normalization =================
// 8 lanes per slot (uint4 = 16B/lane), 8 slots per wave-step; group-combine via
// __shfl_xor butterfly (8,16,32).
__global__ __launch_bounds__(256) void k_agg1(
    const int* __restrict__ offs, const int2* __restrict__ recA,
    const float* __restrict__ es1, const float* __restrict__ sums,
    const __hip_bfloat16* __restrict__ proj1, float* __restrict__ dout) {
  const int lane = threadIdx.x & 63, wid = threadIdx.x >> 6;
  const int n = blockIdx.x * 4 + wid;
  if (n >= NNODES) return;
  const int beg = offs[n], end = offs[n + 1];
  if (beg == end) return;  // dout row already holds skip+bias from k_mm1
  const int g = lane >> 3;  // slot group 0..7
  const int li = lane & 7;  // features li*8 .. li*8+7
  const float sn = sums[n];
  float a0 = 0.f, a1 = 0.f, a2 = 0.f, a3 = 0.f;
  float a4 = 0.f, a5 = 0.f, a6 = 0.f, a7 = 0.f;

#define SLOT(J, LIVE)                                                          \
  {                                                                            \
    const int jj = (J) + g;                                                    \
    const bool lv = (LIVE);                                                    \
    const int js = lv ? jj : beg;                                              \
    const int2 rec = recA[js];                                                 \
    const int o = rec.y & 0x3FFFFFFF;                                          \
    const float e = es1[js];                                                   \
    const float t =                                                            \
        (lv ? e : 0.f) * __builtin_amdgcn_rcpf(sn + sums[o] + 1e-16f);         \
    const uint4 r = *(const uint4*)(proj1 + (size_t)rec.x * 64 + li * 8);      \
    a0 = fmaf(bits2f_lo(r.x), t, a0);                                          \
    a1 = fmaf(bits2f_hi(r.x), t, a1);                                          \
    a2 = fmaf(bits2f_lo(r.y), t, a2);                                          \
    a3 = fmaf(bits2f_hi(r.y), t, a3);                                          \
    a4 = fmaf(bits2f_lo(r.z), t, a4);                                          \
    a5 = fmaf(bits2f_hi(r.z), t, a5);                                          \
    a6 = fmaf(bits2f_lo(r.w), t, a6);                                          \
    a7 = fmaf(bits2f_hi(r.w), t, a7);                                          \
  }

  int j = beg;
  for (; j + 8 <= end; j += 8) SLOT(j, true)
  for (; j < end; j += 8) SLOT(j, jj < end)
#undef SLOT

  // butterfly-reduce across the 8 slot groups
#define RED(m)                                                                 \
  a0 += __shfl_xor(a0, m); a1 += __shfl_xor(a1, m);                            \
  a2 += __shfl_xor(a2, m); a3 += __shfl_xor(a3, m);                            \
  a4 += __shfl_xor(a4, m); a5 += __shfl_xor(a5, m);                            \
  a6 += __shfl_xor(a6, m); a7 += __shfl_xor(a7, m);
  RED(8) RED(16) RED(32)
#undef RED

  if (g == 0) {
    float4* dp = (float4*)(dout + (size_t)n * 64 + li * 8);
    float4 d0 = dp[0], d1 = dp[1];
    d0.x += a0; d0.y += a1; d0.z += a2; d0.w += a3;
    d1.x += a4; d1.y += a5; d1.z += a6; d1.w += a7;
    dp[0] = d0;
    dp[1] = d1;
  }
}

extern "C" void kernel_launch(void* const* d_in, const int* in_sizes, int n_in,
                              void* d_out, int out_size, void* d_ws, size_t ws_size,
                              hipStream_t stream) {
  const float* x = (const float*)d_in[0];
  const int* ei = (const int*)d_in[1];
  const float* W0 = (const float*)d_in[2];
  const float* a10 = (const float*)d_in[3];
  const float* a20 = (const float*)d_in[4];
  const float* a30 = (const float*)d_in[5];
  // d_in[6] = Wskip0: unused (layer-0 skip is identity, F==DIN)
  const float* b0 = (const float*)d_in[7];
  const float* W1 = (const float*)d_in[8];
  const float* a11 = (const float*)d_in[9];
  const float* a21 = (const float*)d_in[10];
  const float* a31 = (const float*)d_in[11];
  const float* Wskip1 = (const float*)d_in[12];
  const float* b1 = (const float*)d_in[13];
  float* out = (float*)d_out;

  // ---- Workspace layout (region sizes unchanged from R8) ----
  unsigned char* proj0f8 = (unsigned char*)d_ws;       // N*256 B (fp8 head-ilv)
  __hip_bfloat16* out0b =
      (__hip_bfloat16*)d_ws + (size_t)NNODES * 256;    // N*256 bf16 (head-ilv)
  float* s1_0 = (float*)(out0b + (size_t)NNODES * 256);  // N*4 x3
  float* s2_0 = s1_0 + (size_t)NNODES * 4;
  float* s3_0 = s2_0 + (size_t)NNODES * 4;
  float* sums0 = s3_0 + (size_t)NNODES * 4;            // N*4
  float* esx0 = sums0 + (size_t)NNODES * 4;            // 2E*4
  int2* recA = (int2*)(esx0 + (size_t)2 * NEDGES * 4); // 2E int2
  int* rcvA = (int*)(recA + 2 * NEDGES);               // 2E
  int* offs = rcvA + 2 * NEDGES;                       // N+16
  float* s1_1 = (float*)(offs + NNODES + 16);          // N x3
  float* s2_1 = s1_1 + NNODES;
  float* s3_1 = s2_1 + NNODES;
  float* sums1 = s3_1 + NNODES;                        // N
  __hip_bfloat16* B0swz = (__hip_bfloat16*)(sums1 + NNODES);  // 17408 bf16
  __hip_bfloat16* B1swz = B0swz + 17408;               // 36864 bf16
  // CSR-build int scratch aliases esx0 (dead until k_esx0):
  int* deg = (int*)esx0;
  int* cursor = deg + NNODES;
  int* bsums = cursor + NNODES;

  __hip_bfloat16* proj1 = (__hip_bfloat16*)d_ws;  // reuse proj0 region (bf16)
  float* es1 = esx0;              // layer-1 exp/att slots (esx0 dead after agg0w)

  // ---- fused weight prep ----
  k_prep<<<212, 256, 0, stream>>>(W0, a10, a20, a30, W1, Wskip1, a11, a21, a31,
                                  B0swz, B1swz);

  // ---- Layer-0 projection + scores via MFMA (fp8 proj0) ----
  k_mm0<<<(NNODES + 63) / 64, 256, 0, stream>>>(x, (const short*)B0swz, proj0f8,
                                                s1_0, s2_0, s3_0);

  // ---- CSR build ----
  hipMemsetAsync(deg, 0, NNODES * sizeof(int), stream);
  k_deg<<<(2 * NEDGES + 255) / 256, 256, 0, stream>>>(ei, deg);
  k_scan1<<<NB_SCAN, 256, 0, stream>>>(deg, offs, bsums);
  k_scan2<<<1, 512, 0, stream>>>(bsums);
  k_scan3<<<NB_SCAN, 256, 0, stream>>>(offs, bsums, cursor);
  k_fill3<<<(2 * NEDGES + 255) / 256, 256, 0, stream>>>(ei, cursor, recA, rcvA);

  // ---- Layer 0: slot exp -> node sums -> fused(att+aggregate, fp8) ----
  const int NBS = (2 * NEDGES + 255) / 256;
  k_esx0<<<NBS, 256, 0, stream>>>(recA, rcvA, s1_0, s2_0, s3_0, esx0);
  k_sums0n<<<NB_SCAN, 256, 0, stream>>>(offs, esx0, sums0);
  k_agg0w<<<(NNODES + 3) / 4, 256, 0, stream>>>(offs, recA, esx0, sums0,
                                                proj0f8, x, b0, out0b);

  // ---- Layer 1: MFMA GEMM -> slot exp -> sums -> fused(att+aggregate) ----
  k_mm1<<<(NNODES + 63) / 64, 256, 0, stream>>>(out0b, (const short*)B1swz, b1,
                                                proj1, out, s1_1, s2_1, s3_1);
  k_esx1<<<NBS, 256, 0, stream>>>(recA, rcvA, s1_1, s2_1, s3_1, es1);
  k_sums1n<<<NB_SCAN, 256, 0, stream>>>(offs, es1, sums1);
  k_agg1<<<(NNODES + 3) / 4, 256, 0, stream>>>(offs, recA, es1, sums1, proj1,
                                               out);
}

// Round 10
// 443.024 us; speedup vs baseline: 1.6450x; 1.0249x over previous
//
#include <hip/hip_runtime.h>
#include <hip/hip_bf16.h>
#include <math.h>

#define NNODES 100000
#define NEDGES 500000
#define NB_SCAN 391  // ceil(NNODES/256)

typedef __attribute__((ext_vector_type(8))) short short8;
typedef __attribute__((ext_vector_type(4))) float f32x4;
typedef __attribute__((ext_vector_type(2))) float f32x2;

__device__ __forceinline__ float bf2f(__hip_bfloat16 v) {
  return __bfloat162float(v);
}
__device__ __forceinline__ unsigned short f2b(float f) {
  __hip_bfloat16 h = __float2bfloat16(f);
  return *(unsigned short*)&h;
}
__device__ __forceinline__ float bits2f_lo(unsigned u) {
  return __uint_as_float(u << 16);
}
__device__ __forceinline__ float bits2f_hi(unsigned u) {
  return __uint_as_float(u & 0xffff0000u);
}

// ================= CSR build ==================================================
__global__ void k_deg(const int* __restrict__ ei, int* __restrict__ deg) {
  const int idx = blockIdx.x * 256 + threadIdx.x;
  if (idx < 2 * NEDGES) atomicAdd(&deg[ei[NEDGES + idx]], 1);
}

__global__ void k_scan1(const int* __restrict__ deg, int* __restrict__ offs,
                        int* __restrict__ bsums) {
  __shared__ int sh[256];
  const int t = threadIdx.x;
  const int i = blockIdx.x * 256 + t;
  const int v = (i < NNODES) ? deg[i] : 0;
  sh[t] = v;
  __syncthreads();
  for (int d = 1; d < 256; d <<= 1) {
    const int add = (t >= d) ? sh[t - d] : 0;
    __syncthreads();
    sh[t] += add;
    __syncthreads();
  }
  if (i < NNODES) offs[i] = sh[t] - v;  // exclusive
  if (t == 255) bsums[blockIdx.x] = sh[255];
}

__global__ void k_scan2(int* __restrict__ bsums) {
  __shared__ int sh[512];
  const int t = threadIdx.x;
  const int v = (t < NB_SCAN) ? bsums[t] : 0;
  sh[t] = v;
  __syncthreads();
  for (int d = 1; d < 512; d <<= 1) {
    const int add = (t >= d) ? sh[t - d] : 0;
    __syncthreads();
    sh[t] += add;
    __syncthreads();
  }
  if (t < NB_SCAN) bsums[t] = sh[t] - v;  // exclusive
}

__global__ void k_scan3(int* __restrict__ offs, const int* __restrict__ bsums,
                        int* __restrict__ cursor) {
  const int i = blockIdx.x * 256 + threadIdx.x;
  if (i < NNODES) {
    const int o = offs[i] + bsums[blockIdx.x];
    offs[i] = o;
    cursor[i] = o;
  }
  if (i == 0) offs[NNODES] = 2 * NEDGES;
}

// Fill slot records: recA=(drug, other|role<<30), rcvA=receiver node.
__global__ void k_fill3(const int* __restrict__ ei, int* __restrict__ cursor,
                        int2* __restrict__ recA, int* __restrict__ rcvA) {
  const int idx = blockIdx.x * 256 + threadIdx.x;
  if (idx >= 2 * NEDGES) return;
  const int n = ei[NEDGES + idx];
  const int e = (idx < NEDGES) ? idx : idx - NEDGES;
  const int drug = ei[e];
  const int other = (idx < NEDGES) ? ei[2 * NEDGES + e] : ei[NEDGES + e];
  const int role = (idx < NEDGES) ? 0 : 1;
  const int pos = atomicAdd(&cursor[n], 1);
  recA[pos] = make_int2(drug, other | (role << 30));
  rcvA[pos] = n;
}

// ========== Fused B-matrix prep: blocks 0..67 -> B0 (layer 0), rest -> B1 =====
__global__ void k_prep(const float* __restrict__ W0, const float* __restrict__ a10,
                       const float* __restrict__ a20, const float* __restrict__ a30,
                       const float* __restrict__ W1, const float* __restrict__ Wsk,
                       const float* __restrict__ a11, const float* __restrict__ a21,
                       const float* __restrict__ a31,
                       __hip_bfloat16* __restrict__ B0,
                       __hip_bfloat16* __restrict__ B1) {
  if (blockIdx.x < 68) {
    const int t = blockIdx.x * 256 + threadIdx.x;  // < 17408
    const int j = t & 7, l = (t >> 3) & 63, s = (t >> 9) & 1, g = t >> 10;
    const int k = s * 32 + ((l >> 4) << 3) + j;
    const int col = g * 16 + (l & 15);
    float v = 0.f;
    if (col < 256) {
      v = W0[col * 64 + k];
    } else if (col < 268) {
      const int idx = col - 256;
      const int r = idx >> 2, h = idx & 3;
      const float* av = (r == 0) ? a10 : (r == 1) ? a20 : a30;
      for (int f = 0; f < 64; ++f)
        v = fmaf(av[h * 64 + f], W0[(h * 64 + f) * 64 + k], v);
    }
    B0[t] = __float2bfloat16(v);
  } else {
    const int t = (blockIdx.x - 68) * 256 + threadIdx.x;  // < 36864
    const int j = t & 7, l = (t >> 3) & 63, s = (t >> 9) & 7, g = t >> 12;
    const int kp = s * 32 + ((l >> 4) << 3) + j;
    const int k = (kp & 3) * 64 + (kp >> 2);  // permuted -> original (head-ilv A)
    const int col = g * 16 + (l & 15);
    float v = 0.f;
    if (col < 64) {
      v = W1[col * 256 + k];
    } else if (col < 128) {
      v = Wsk[(col - 64) * 256 + k];
    } else if (col < 131) {
      const int r = col - 128;
      const float* av = (r == 0) ? a11 : (r == 1) ? a21 : a31;
      for (int f = 0; f < 64; ++f) v = fmaf(av[f], W1[f * 256 + k], v);
    }
    B1[t] = __float2bfloat16(v);
  }
}

// ================= Layer-0 MFMA GEMM: [N,64] x [64,272] =======================
// proj0 stored FP8 e4m3, HEAD-INTERLEAVED: proj0f8[n*256 + f*4 + h] (1B each).
#define LDA0 72
__global__ __launch_bounds__(256) void k_mm0(
    const float* __restrict__ x, const short* __restrict__ B0,
    unsigned char* __restrict__ proj0f8, float* __restrict__ s1,
    float* __restrict__ s2, float* __restrict__ s3) {
  __shared__ __hip_bfloat16 As[64 * LDA0];
  const int t = threadIdx.x;
  const int lane = t & 63, w = t >> 6;
  const int base = blockIdx.x * 64;
  for (int q = 0; q < 4; ++q) {
    const int i = q * 256 + t;
    const int r = i >> 4;
    const int c4 = i & 15;
    int rg = base + r;
    if (rg >= NNODES) rg = NNODES - 1;
    const float4 v = ((const float4*)(x + (size_t)rg * 64))[c4];
    __hip_bfloat16* dst = &As[r * LDA0 + c4 * 4];
    dst[0] = __float2bfloat16(v.x);
    dst[1] = __float2bfloat16(v.y);
    dst[2] = __float2bfloat16(v.z);
    dst[3] = __float2bfloat16(v.w);
  }
  __syncthreads();
  const short8* B8 = (const short8*)B0;
  f32x4 acc[17];
#pragma unroll
  for (int g = 0; g < 17; ++g) acc[g] = (f32x4){0.f, 0.f, 0.f, 0.f};
  const int aoff = (w * 16 + (lane & 15)) * LDA0 + (lane >> 4) * 8;
#pragma unroll
  for (int s = 0; s < 2; ++s) {
    const short8 af = *(const short8*)(&As[aoff + s * 32]);
#pragma unroll
    for (int g = 0; g < 17; ++g) {
      const short8 bf = B8[(g * 2 + s) * 64 + lane];
      acc[g] = __builtin_amdgcn_mfma_f32_16x16x32_bf16(af, bf, acc[g], 0, 0, 0);
    }
  }
  const int r0 = base + w * 16 + (lane >> 4) * 4;
  const int cn = lane & 15;
  // packed fp8 epilogue: heads h of feature f=g*16+cn are acc[g+4h]
#pragma unroll
  for (int g = 0; g < 4; ++g) {
    const int f = g * 16 + cn;
#pragma unroll
    for (int r = 0; r < 4; ++r) {
      const int row = r0 + r;
      if (row < NNODES) {
        unsigned o = __builtin_amdgcn_cvt_pk_fp8_f32(acc[g][r], acc[g + 4][r],
                                                     0u, false);
        o = __builtin_amdgcn_cvt_pk_fp8_f32(acc[g + 8][r], acc[g + 12][r], o,
                                            true);
        *(unsigned*)(proj0f8 + (size_t)row * 256 + f * 4) = o;
      }
    }
  }
#pragma unroll
  for (int r = 0; r < 4; ++r) {
    const int row = r0 + r;
    if (row < NNODES) {
      if (cn < 4) s1[row * 4 + cn] = acc[16][r];
      else if (cn < 8) s2[row * 4 + (cn - 4)] = acc[16][r];
      else if (cn < 12) s3[row * 4 + (cn - 8)] = acc[16][r];
    }
  }
}

// ====== Layer-0 exp-scores, SLOT-PARALLEL (no loops) ==========================
__global__ void k_esx0(const int2* __restrict__ recA, const int* __restrict__ rcvA,
                       const float* __restrict__ s1, const float* __restrict__ s2,
                       const float* __restrict__ s3, float* __restrict__ esx) {
  const int j = blockIdx.x * 256 + threadIdx.x;
  if (j >= 2 * NEDGES) return;
  const int2 rec = recA[j];
  const int n = rcvA[j];
  const int o = rec.y & 0x3FFFFFFF;
  const int role = rec.y >> 30;
  const float4 A = ((const float4*)s1)[rec.x];
  const float4 T = ((const float4*)s2)[role ? o : n];
  const float4 D = ((const float4*)s3)[role ? n : o];
  float4 es;
  float s;
  s = A.x + T.x + D.x; s = s > 0.f ? s : 0.2f * s; es.x = __expf(s);
  s = A.y + T.y + D.y; s = s > 0.f ? s : 0.2f * s; es.y = __expf(s);
  s = A.z + T.z + D.z; s = s > 0.f ? s : 0.2f * s; es.z = __expf(s);
  s = A.w + T.w + D.w; s = s > 0.f ? s : 0.2f * s; es.w = __expf(s);
  ((float4*)esx)[j] = es;
}

// ====== Layer-0 denominator sums: per node, sequential esx reads ==============
__global__ void k_sums0n(const int* __restrict__ offs, const float* __restrict__ esx,
                         float* __restrict__ sums) {
  const int n = blockIdx.x * 256 + threadIdx.x;
  if (n >= NNODES) return;
  const int beg = offs[n], end = offs[n + 1];
  float4 acc = make_float4(0.f, 0.f, 0.f, 0.f);
  for (int j = beg; j < end; ++j) {
    const float4 v = ((const float4*)esx)[j];
    acc.x += v.x; acc.y += v.y; acc.z += v.z; acc.w += v.w;
  }
  ((float4*)sums)[n] = acc;
}

// ====== Layer-0 aggregate, wave/node, FUSED norm, FP8, 4 slots/step ===========
// 16 lanes per slot (uint4 = 16B/lane = 256B row), 4 slots per wave-step;
// group-combine via __shfl_xor(16,32). Epilogue spread over ALL 64 lanes:
// lane (g,li) handles feature f=li*4+g (4 head-values), one 8B store.
__global__ __launch_bounds__(256) void k_agg0w(
    const int* __restrict__ offs, const int2* __restrict__ recA,
    const float* __restrict__ esx, const float* __restrict__ sums,
    const unsigned char* __restrict__ proj0f8, const float* __restrict__ x,
    const float* __restrict__ b0, __hip_bfloat16* __restrict__ out0b) {
  const int lane = threadIdx.x & 63, wid = threadIdx.x >> 6;
  const int n = blockIdx.x * 4 + wid;
  if (n >= NNODES) return;
  const int beg = offs[n], end = offs[n + 1];
  const int g = lane >> 4;   // slot group 0..3
  const int li = lane & 15;  // 16B chunk: row bytes li*16 .. li*16+15
  const float4 sn = ((const float4*)sums)[n];
  // acc: word w (feature li*4+w), component = head 0..3
  f32x4 a0 = (f32x4){0.f, 0.f, 0.f, 0.f};
  f32x4 a1 = (f32x4){0.f, 0.f, 0.f, 0.f};
  f32x4 a2 = (f32x4){0.f, 0.f, 0.f, 0.f};
  f32x4 a3 = (f32x4){0.f, 0.f, 0.f, 0.f};

#define STEP(J, LIVE)                                                          \
  {                                                                            \
    const int jj = (J) + g;                                                    \
    const bool lv = (LIVE);                                                    \
    const int js = lv ? jj : beg;                                              \
    const int2 rec = recA[js];                                                 \
    const int o = rec.y & 0x3FFFFFFF;                                          \
    const float4 e = ((const float4*)esx)[js];                                 \
    const float4 so = ((const float4*)sums)[o];                                \
    const uint4 r = *(const uint4*)(proj0f8 + (size_t)rec.x * 256 + li * 16);  \
    const float lm = lv ? 1.f : 0.f;                                           \
    const float t0 = lm * e.x * __builtin_amdgcn_rcpf(sn.x + so.x + 1e-16f);   \
    const float t1 = lm * e.y * __builtin_amdgcn_rcpf(sn.y + so.y + 1e-16f);   \
    const float t2 = lm * e.z * __builtin_amdgcn_rcpf(sn.z + so.z + 1e-16f);   \
    const float t3 = lm * e.w * __builtin_amdgcn_rcpf(sn.w + so.w + 1e-16f);   \
    f32x2 c;                                                                   \
    c = __builtin_amdgcn_cvt_pk_f32_fp8(r.x, false);                           \
    a0[0] = fmaf(c[0], t0, a0[0]); a0[1] = fmaf(c[1], t1, a0[1]);              \
    c = __builtin_amdgcn_cvt_pk_f32_fp8(r.x, true);                            \
    a0[2] = fmaf(c[0], t2, a0[2]); a0[3] = fmaf(c[1], t3, a0[3]);              \
    c = __builtin_amdgcn_cvt_pk_f32_fp8(r.y, false);                           \
    a1[0] = fmaf(c[0], t0, a1[0]); a1[1] = fmaf(c[1], t1, a1[1]);              \
    c = __builtin_amdgcn_cvt_pk_f32_fp8(r.y, true);                            \
    a1[2] = fmaf(c[0], t2, a1[2]); a1[3] = fmaf(c[1], t3, a1[3]);              \
    c = __builtin_amdgcn_cvt_pk_f32_fp8(r.z, false);                           \
    a2[0] = fmaf(c[0], t0, a2[0]); a2[1] = fmaf(c[1], t1, a2[1]);              \
    c = __builtin_amdgcn_cvt_pk_f32_fp8(r.z, true);                            \
    a2[2] = fmaf(c[0], t2, a2[2]); a2[3] = fmaf(c[1], t3, a2[3]);              \
    c = __builtin_amdgcn_cvt_pk_f32_fp8(r.w, false);                           \
    a3[0] = fmaf(c[0], t0, a3[0]); a3[1] = fmaf(c[1], t1, a3[1]);              \
    c = __builtin_amdgcn_cvt_pk_f32_fp8(r.w, true);                            \
    a3[2] = fmaf(c[0], t2, a3[2]); a3[3] = fmaf(c[1], t3, a3[3]);              \
  }

  int j = beg;
  for (; j + 8 <= end; j += 8) {
    STEP(j, true)
    STEP(j + 4, true)
  }
  for (; j < end; j += 4) STEP(j, jj < end)
#undef STEP

  // combine the four slot-groups (all lanes end with full a0..a3)
#define RED(m)                                                                 \
  a0[0] += __shfl_xor(a0[0], m); a0[1] += __shfl_xor(a0[1], m);                \
  a0[2] += __shfl_xor(a0[2], m); a0[3] += __shfl_xor(a0[3], m);                \
  a1[0] += __shfl_xor(a1[0], m); a1[1] += __shfl_xor(a1[1], m);                \
  a1[2] += __shfl_xor(a1[2], m); a1[3] += __shfl_xor(a1[3], m);                \
  a2[0] += __shfl_xor(a2[0], m); a2[1] += __shfl_xor(a2[1], m);                \
  a2[2] += __shfl_xor(a2[2], m); a2[3] += __shfl_xor(a2[3], m);                \
  a3[0] += __shfl_xor(a3[0], m); a3[1] += __shfl_xor(a3[1], m);                \
  a3[2] += __shfl_xor(a3[2], m); a3[3] += __shfl_xor(a3[3], m);
  RED(16) RED(32)
#undef RED

  // epilogue on ALL 64 lanes: lane (g,li) -> feature f = li*4 + g
  const f32x4 aw = (g == 0) ? a0 : (g == 1) ? a1 : (g == 2) ? a2 : a3;
  const int f = li * 4 + g;
  const float xf = x[(size_t)n * 64 + f];
  const float e0 = aw[0] + xf + b0[f];
  const float e1 = aw[1] + xf + b0[64 + f];
  const float e2 = aw[2] + xf + b0[128 + f];
  const float e3 = aw[3] + xf + b0[192 + f];
#define EL(v_) ((v_) > 0.f ? (v_) : (__expf(v_) - 1.f))
  const float w0 = EL(e0);
  const float w1 = EL(e1);
  const float w2 = EL(e2);
  const float w3 = EL(e3);
#undef EL
  uint2 o;
  o.x = (unsigned)f2b(w0) | ((unsigned)f2b(w1) << 16);
  o.y = (unsigned)f2b(w2) | ((unsigned)f2b(w3) << 16);
  *(uint2*)(out0b + (size_t)n * 256 + f * 4) = o;
}

// ====== Layer-1 MFMA GEMM: [N,256] x [256,144] (k-permuted B) =================
#define LDA1 264
__global__ __launch_bounds__(256) void k_mm1(
    const __hip_bfloat16* __restrict__ hsrc, const short* __restrict__ B1,
    const float* __restrict__ b1, __hip_bfloat16* __restrict__ proj1,
    float* __restrict__ out, float* __restrict__ s1, float* __restrict__ s2,
    float* __restrict__ s3) {
  __shared__ short As[64 * LDA1];
  const int t = threadIdx.x;
  const int lane = t & 63, w = t >> 6;
  const int base = blockIdx.x * 64;
  for (int q = 0; q < 8; ++q) {
    const int i = q * 256 + t;
    const int r = i >> 5;
    const int c = (i & 31) * 8;
    int rg = base + r;
    if (rg >= NNODES) rg = NNODES - 1;
    const float4 v = *(const float4*)((const short*)hsrc + (size_t)rg * 256 + c);
    *(float4*)(&As[r * LDA1 + c]) = v;
  }
  __syncthreads();
  const short8* B8 = (const short8*)B1;
  f32x4 acc[9];
#pragma unroll
  for (int g = 0; g < 9; ++g) acc[g] = (f32x4){0.f, 0.f, 0.f, 0.f};
  const int aoff = (w * 16 + (lane & 15)) * LDA1 + (lane >> 4) * 8;
#pragma unroll
  for (int s = 0; s < 8; ++s) {
    const short8 af = *(const short8*)(&As[aoff + s * 32]);
#pragma unroll
    for (int g = 0; g < 9; ++g) {
      const short8 bf = B8[(g * 8 + s) * 64 + lane];
      acc[g] = __builtin_amdgcn_mfma_f32_16x16x32_bf16(af, bf, acc[g], 0, 0, 0);
    }
  }
  const int r0 = base + w * 16 + (lane >> 4) * 4;
  const int cn = lane & 15;
#pragma unroll
  for (int g = 0; g < 4; ++g) {
    const int col = g * 16 + cn;
#pragma unroll
    for (int r = 0; r < 4; ++r) {
      const int row = r0 + r;
      if (row < NNODES)
        proj1[(size_t)row * 64 + col] = __float2bfloat16(acc[g][r]);
    }
  }
#pragma unroll
  for (int g = 4; g < 8; ++g) {
    const int col = (g - 4) * 16 + cn;
    const float bv = b1[col];
#pragma unroll
    for (int r = 0; r < 4; ++r) {
      const int row = r0 + r;
      if (row < NNODES) out[(size_t)row * 64 + col] = acc[g][r] + bv;
    }
  }
#pragma unroll
  for (int r = 0; r < 4; ++r) {
    const int row = r0 + r;
    if (row < NNODES) {
      if (cn == 0) s1[row] = acc[8][r];
      else if (cn == 1) s2[row] = acc[8][r];
      else if (cn == 2) s3[row] = acc[8][r];
    }
  }
}

// ====== Layer-1 exp-scores, SLOT-PARALLEL =====================================
__global__ void k_esx1(const int2* __restrict__ recA, const int* __restrict__ rcvA,
                       const float* __restrict__ s1, const float* __restrict__ s2,
                       const float* __restrict__ s3, float* __restrict__ es1) {
  const int j = blockIdx.x * 256 + threadIdx.x;
  if (j >= 2 * NEDGES) return;
  const int2 rec = recA[j];
  const int n = rcvA[j];
  const int o = rec.y & 0x3FFFFFFF;
  const int role = rec.y >> 30;
  float s = s1[rec.x] + s2[role ? o : n] + s3[role ? n : o];
  s = s > 0.f ? s : 0.2f * s;
  es1[j] = __expf(s);
}

// ====== Layer-1 denominator sums: per node, sequential ========================
__global__ void k_sums1n(const int* __restrict__ offs, const float* __restrict__ es1,
                         float* __restrict__ sums) {
  const int n = blockIdx.x * 256 + threadIdx.x;
  if (n >= NNODES) return;
  const int beg = offs[n], end = offs[n + 1];
  float acc = 0.f;
  for (int j = beg; j < end; ++j) acc += es1[j];
  sums[n] = acc;
}

// ========== Layer-1 aggregate, wave/node, FUSED normalization =================
// 8 lanes per slot (uint4 = 16B/lane), 8 slots per wave-step; group-combine via
// __shfl_xor butterfly (8,16,32).
__global__ __launch_bounds__(256) void k_agg1(
    const int* __restrict__ offs, const int2* __restrict__ recA,
    const float* __restrict__ es1, const float* __restrict__ sums,
    const __hip_bfloat16* __restrict__ proj1, float* __restrict__ dout) {
  const int lane = threadIdx.x & 63, wid = threadIdx.x >> 6;
  const int n = blockIdx.x * 4 + wid;
  if (n >= NNODES) return;
  const int beg = offs[n], end = offs[n + 1];
  if (beg == end) return;  // dout row already holds skip+bias from k_mm1
  const int g = lane >> 3;  // slot group 0..7
  const int li = lane & 7;  // features li*8 .. li*8+7
  const float sn = sums[n];
  float a0 = 0.f, a1 = 0.f, a2 = 0.f, a3 = 0.f;
  float a4 = 0.f, a5 = 0.f, a6 = 0.f, a7 = 0.f;

#define SLOT(J, LIVE)                                                          \
  {                                                                            \
    const int jj = (J) + g;                                                    \
    const bool lv = (LIVE);                                                    \
    const int js = lv ? jj : beg;                                              \
    const int2 rec = recA[js];                                                 \
    const int o = rec.y & 0x3FFFFFFF;                                          \
    const float e = es1[js];                                                   \
    const float t =                                                            \
        (lv ? e : 0.f) * __builtin_amdgcn_rcpf(sn + sums[o] + 1e-16f);         \
    const uint4 r = *(const uint4*)(proj1 + (size_t)rec.x * 64 + li * 8);      \
    a0 = fmaf(bits2f_lo(r.x), t, a0);                                          \
    a1 = fmaf(bits2f_hi(r.x), t, a1);                                          \
    a2 = fmaf(bits2f_lo(r.y), t, a2);                                          \
    a3 = fmaf(bits2f_hi(r.y), t, a3);                                          \
    a4 = fmaf(bits2f_lo(r.z), t, a4);                                          \
    a5 = fmaf(bits2f_hi(r.z), t, a5);                                          \
    a6 = fmaf(bits2f_lo(r.w), t, a6);                                          \
    a7 = fmaf(bits2f_hi(r.w), t, a7);                                          \
  }

  int j = beg;
  for (; j + 8 <= end; j += 8) SLOT(j, true)
  for (; j < end; j += 8) SLOT(j, jj < end)
#undef SLOT

  // butterfly-reduce across the 8 slot groups
#define RED(m)                                                                 \
  a0 += __shfl_xor(a0, m); a1 += __shfl_xor(a1, m);                            \
  a2 += __shfl_xor(a2, m); a3 += __shfl_xor(a3, m);                            \
  a4 += __shfl_xor(a4, m); a5 += __shfl_xor(a5, m);                            \
  a6 += __shfl_xor(a6, m); a7 += __shfl_xor(a7, m);
  RED(8) RED(16) RED(32)
#undef RED

  if (g == 0) {
    float4* dp = (float4*)(dout + (size_t)n * 64 + li * 8);
    float4 d0 = dp[0], d1 = dp[1];
    d0.x += a0; d0.y += a1; d0.z += a2; d0.w += a3;
    d1.x += a4; d1.y += a5; d1.z += a6; d1.w += a7;
    dp[0] = d0;
    dp[1] = d1;
  }
}

extern "C" void kernel_launch(void* const* d_in, const int* in_sizes, int n_in,
                              void* d_out, int out_size, void* d_ws, size_t ws_size,
                              hipStream_t stream) {
  const float* x = (const float*)d_in[0];
  const int* ei = (const int*)d_in[1];
  const float* W0 = (const float*)d_in[2];
  const float* a10 = (const float*)d_in[3];
  const float* a20 = (const float*)d_in[4];
  const float* a30 = (const float*)d_in[5];
  // d_in[6] = Wskip0: unused (layer-0 skip is identity, F==DIN)
  const float* b0 = (const float*)d_in[7];
  const float* W1 = (const float*)d_in[8];
  const float* a11 = (const float*)d_in[9];
  const float* a21 = (const float*)d_in[10];
  const float* a31 = (const float*)d_in[11];
  const float* Wskip1 = (const float*)d_in[12];
  const float* b1 = (const float*)d_in[13];
  float* out = (float*)d_out;

  // ---- Workspace layout (region sizes unchanged from R9) ----
  unsigned char* proj0f8 = (unsigned char*)d_ws;       // N*256 B (fp8 head-ilv)
  __hip_bfloat16* out0b =
      (__hip_bfloat16*)d_ws + (size_t)NNODES * 256;    // N*256 bf16 (head-ilv)
  float* s1_0 = (float*)(out0b + (size_t)NNODES * 256);  // N*4 x3
  float* s2_0 = s1_0 + (size_t)NNODES * 4;
  float* s3_0 = s2_0 + (size_t)NNODES * 4;
  float* sums0 = s3_0 + (size_t)NNODES * 4;            // N*4
  float* esx0 = sums0 + (size_t)NNODES * 4;            // 2E*4
  int2* recA = (int2*)(esx0 + (size_t)2 * NEDGES * 4); // 2E int2
  int* rcvA = (int*)(recA + 2 * NEDGES);               // 2E
  int* offs = rcvA + 2 * NEDGES;                       // N+16
  float* s1_1 = (float*)(offs + NNODES + 16);          // N x3
  float* s2_1 = s1_1 + NNODES;
  float* s3_1 = s2_1 + NNODES;
  float* sums1 = s3_1 + NNODES;                        // N
  __hip_bfloat16* B0swz = (__hip_bfloat16*)(sums1 + NNODES);  // 17408 bf16
  __hip_bfloat16* B1swz = B0swz + 17408;               // 36864 bf16
  // CSR-build int scratch aliases esx0 (dead until k_esx0):
  int* deg = (int*)esx0;
  int* cursor = deg + NNODES;
  int* bsums = cursor + NNODES;

  __hip_bfloat16* proj1 = (__hip_bfloat16*)d_ws;  // reuse proj0 region (bf16)
  float* es1 = esx0;              // layer-1 exp/att slots (esx0 dead after agg0w)

  // ---- fused weight prep ----
  k_prep<<<212, 256, 0, stream>>>(W0, a10, a20, a30, W1, Wskip1, a11, a21, a31,
                                  B0swz, B1swz);

  // ---- Layer-0 projection + scores via MFMA (fp8 proj0) ----
  k_mm0<<<(NNODES + 63) / 64, 256, 0, stream>>>(x, (const short*)B0swz, proj0f8,
                                                s1_0, s2_0, s3_0);

  // ---- CSR build ----
  hipMemsetAsync(deg, 0, NNODES * sizeof(int), stream);
  k_deg<<<(2 * NEDGES + 255) / 256, 256, 0, stream>>>(ei, deg);
  k_scan1<<<NB_SCAN, 256, 0, stream>>>(deg, offs, bsums);
  k_scan2<<<1, 512, 0, stream>>>(bsums);
  k_scan3<<<NB_SCAN, 256, 0, stream>>>(offs, bsums, cursor);
  k_fill3<<<(2 * NEDGES + 255) / 256, 256, 0, stream>>>(ei, cursor, recA, rcvA);

  // ---- Layer 0: slot exp -> node sums -> fused(att+aggregate, fp8) ----
  const int NBS = (2 * NEDGES + 255) / 256;
  k_esx0<<<NBS, 256, 0, stream>>>(recA, rcvA, s1_0, s2_0, s3_0, esx0);
  k_sums0n<<<NB_SCAN, 256, 0, stream>>>(offs, esx0, sums0);
  k_agg0w<<<(NNODES + 3) / 4, 256, 0, stream>>>(offs, recA, esx0, sums0,
                                                proj0f8, x, b0, out0b);

  // ---- Layer 1: MFMA GEMM -> slot exp -> sums -> fused(att+aggregate) ----
  k_mm1<<<(NNODES + 63) / 64, 256, 0, stream>>>(out0b, (const short*)B1swz, b1,
                                                proj1, out, s1_1, s2_1, s3_1);
  k_esx1<<<NBS, 256, 0, stream>>>(recA, rcvA, s1_1, s2_1, s3_1, es1);
  k_sums1n<<<NB_SCAN, 256, 0, stream>>>(offs, es1, sums1);
  k_agg1<<<(NNODES + 3) / 4, 256, 0, stream>>>(offs, recA, es1, sums1, proj1,
                                               out);
}

// Round 12
// 438.328 us; speedup vs baseline: 1.6627x; 1.0107x over previous
//
#include <hip/hip_runtime.h>
#include <hip/hip_bf16.h>
#include <math.h>

#define NNODES 100000
#define NEDGES 500000
#define NB_SCAN 391  // ceil(NNODES/256)

typedef __attribute__((ext_vector_type(8))) short short8;
typedef __attribute__((ext_vector_type(4))) float f32x4;
typedef __attribute__((ext_vector_type(2))) float f32x2;

__device__ __forceinline__ float bf2f(__hip_bfloat16 v) {
  return __bfloat162float(v);
}
__device__ __forceinline__ unsigned short f2b(float f) {
  __hip_bfloat16 h = __float2bfloat16(f);
  return *(unsigned short*)&h;
}
__device__ __forceinline__ float bits2f_lo(unsigned u) {
  return __uint_as_float(u << 16);
}
__device__ __forceinline__ float bits2f_hi(unsigned u) {
  return __uint_as_float(u & 0xffff0000u);
}

// ================= CSR build ==================================================
__global__ void k_deg(const int* __restrict__ ei, int* __restrict__ deg) {
  const int idx = blockIdx.x * 256 + threadIdx.x;
  if (idx < 2 * NEDGES) atomicAdd(&deg[ei[NEDGES + idx]], 1);
}

__global__ void k_scan1(const int* __restrict__ deg, int* __restrict__ offs,
                        int* __restrict__ bsums) {
  __shared__ int sh[256];
  const int t = threadIdx.x;
  const int i = blockIdx.x * 256 + t;
  const int v = (i < NNODES) ? deg[i] : 0;
  sh[t] = v;
  __syncthreads();
  for (int d = 1; d < 256; d <<= 1) {
    const int add = (t >= d) ? sh[t - d] : 0;
    __syncthreads();
    sh[t] += add;
    __syncthreads();
  }
  if (i < NNODES) offs[i] = sh[t] - v;  // exclusive
  if (t == 255) bsums[blockIdx.x] = sh[255];
}

__global__ void k_scan2(int* __restrict__ bsums) {
  __shared__ int sh[512];
  const int t = threadIdx.x;
  const int v = (t < NB_SCAN) ? bsums[t] : 0;
  sh[t] = v;
  __syncthreads();
  for (int d = 1; d < 512; d <<= 1) {
    const int add = (t >= d) ? sh[t - d] : 0;
    __syncthreads();
    sh[t] += add;
    __syncthreads();
  }
  if (t < NB_SCAN) bsums[t] = sh[t] - v;  // exclusive
}

__global__ void k_scan3(int* __restrict__ offs, const int* __restrict__ bsums,
                        int* __restrict__ cursor) {
  const int i = blockIdx.x * 256 + threadIdx.x;
  if (i < NNODES) {
    const int o = offs[i] + bsums[blockIdx.x];
    offs[i] = o;
    cursor[i] = o;
  }
  if (i == 0) offs[NNODES] = 2 * NEDGES;
}

// Fill slot records: recA=(drug, other|role<<30), rcvA=receiver node.
__global__ void k_fill3(const int* __restrict__ ei, int* __restrict__ cursor,
                        int2* __restrict__ recA, int* __restrict__ rcvA) {
  const int idx = blockIdx.x * 256 + threadIdx.x;
  if (idx >= 2 * NEDGES) return;
  const int n = ei[NEDGES + idx];
  const int e = (idx < NEDGES) ? idx : idx - NEDGES;
  const int drug = ei[e];
  const int other = (idx < NEDGES) ? ei[2 * NEDGES + e] : ei[NEDGES + e];
  const int role = (idx < NEDGES) ? 0 : 1;
  const int pos = atomicAdd(&cursor[n], 1);
  recA[pos] = make_int2(drug, other | (role << 30));
  rcvA[pos] = n;
}

// ========== Fused B-matrix prep: blocks 0..67 -> B0 (layer 0), rest -> B1 =====
__global__ void k_prep(const float* __restrict__ W0, const float* __restrict__ a10,
                       const float* __restrict__ a20, const float* __restrict__ a30,
                       const float* __restrict__ W1, const float* __restrict__ Wsk,
                       const float* __restrict__ a11, const float* __restrict__ a21,
                       const float* __restrict__ a31,
                       __hip_bfloat16* __restrict__ B0,
                       __hip_bfloat16* __restrict__ B1) {
  if (blockIdx.x < 68) {
    const int t = blockIdx.x * 256 + threadIdx.x;  // < 17408
    const int j = t & 7, l = (t >> 3) & 63, s = (t >> 9) & 1, g = t >> 10;
    const int k = s * 32 + ((l >> 4) << 3) + j;
    const int col = g * 16 + (l & 15);
    float v = 0.f;
    if (col < 256) {
      v = W0[col * 64 + k];
    } else if (col < 268) {
      const int idx = col - 256;
      const int r = idx >> 2, h = idx & 3;
      const float* av = (r == 0) ? a10 : (r == 1) ? a20 : a30;
      for (int f = 0; f < 64; ++f)
        v = fmaf(av[h * 64 + f], W0[(h * 64 + f) * 64 + k], v);
    }
    B0[t] = __float2bfloat16(v);
  } else {
    const int t = (blockIdx.x - 68) * 256 + threadIdx.x;  // < 36864
    const int j = t & 7, l = (t >> 3) & 63, s = (t >> 9) & 7, g = t >> 12;
    const int kp = s * 32 + ((l >> 4) << 3) + j;
    const int k = (kp & 3) * 64 + (kp >> 2);  // permuted -> original (head-ilv A)
    const int col = g * 16 + (l & 15);
    float v = 0.f;
    if (col < 64) {
      v = W1[col * 256 + k];
    } else if (col < 128) {
      v = Wsk[(col - 64) * 256 + k];
    } else if (col < 131) {
      const int r = col - 128;
      const float* av = (r == 0) ? a11 : (r == 1) ? a21 : a31;
      for (int f = 0; f < 64; ++f) v = fmaf(av[f], W1[f * 256 + k], v);
    }
    B1[t] = __float2bfloat16(v);
  }
}

// ================= Layer-0 MFMA GEMM: [N,64] x [64,272] =======================
// proj0 stored FP8 e4m3, HEAD-INTERLEAVED: proj0f8[n*256 + f*4 + h] (1B each).
#define LDA0 72
__global__ __launch_bounds__(256) void k_mm0(
    const float* __restrict__ x, const short* __restrict__ B0,
    unsigned char* __restrict__ proj0f8, float* __restrict__ s1,
    float* __restrict__ s2, float* __restrict__ s3) {
  __shared__ __hip_bfloat16 As[64 * LDA0];
  const int t = threadIdx.x;
  const int lane = t & 63, w = t >> 6;
  const int base = blockIdx.x * 64;
  for (int q = 0; q < 4; ++q) {
    const int i = q * 256 + t;
    const int r = i >> 4;
    const int c4 = i & 15;
    int rg = base + r;
    if (rg >= NNODES) rg = NNODES - 1;
    const float4 v = ((const float4*)(x + (size_t)rg * 64))[c4];
    __hip_bfloat16* dst = &As[r * LDA0 + c4 * 4];
    dst[0] = __float2bfloat16(v.x);
    dst[1] = __float2bfloat16(v.y);
    dst[2] = __float2bfloat16(v.z);
    dst[3] = __float2bfloat16(v.w);
  }
  __syncthreads();
  const short8* B8 = (const short8*)B0;
  f32x4 acc[17];
#pragma unroll
  for (int g = 0; g < 17; ++g) acc[g] = (f32x4){0.f, 0.f, 0.f, 0.f};
  const int aoff = (w * 16 + (lane & 15)) * LDA0 + (lane >> 4) * 8;
#pragma unroll
  for (int s = 0; s < 2; ++s) {
    const short8 af = *(const short8*)(&As[aoff + s * 32]);
#pragma unroll
    for (int g = 0; g < 17; ++g) {
      const short8 bf = B8[(g * 2 + s) * 64 + lane];
      acc[g] = __builtin_amdgcn_mfma_f32_16x16x32_bf16(af, bf, acc[g], 0, 0, 0);
    }
  }
  const int r0 = base + w * 16 + (lane >> 4) * 4;
  const int cn = lane & 15;
  // packed fp8 epilogue: heads h of feature f=g*16+cn are acc[g+4h]
#pragma unroll
  for (int g = 0; g < 4; ++g) {
    const int f = g * 16 + cn;
#pragma unroll
    for (int r = 0; r < 4; ++r) {
      const int row = r0 + r;
      if (row < NNODES) {
        unsigned o = __builtin_amdgcn_cvt_pk_fp8_f32(acc[g][r], acc[g + 4][r],
                                                     0u, false);
        o = __builtin_amdgcn_cvt_pk_fp8_f32(acc[g + 8][r], acc[g + 12][r], o,
                                            true);
        *(unsigned*)(proj0f8 + (size_t)row * 256 + f * 4) = o;
      }
    }
  }
#pragma unroll
  for (int r = 0; r < 4; ++r) {
    const int row = r0 + r;
    if (row < NNODES) {
      if (cn < 4) s1[row * 4 + cn] = acc[16][r];
      else if (cn < 8) s2[row * 4 + (cn - 4)] = acc[16][r];
      else if (cn < 12) s3[row * 4 + (cn - 8)] = acc[16][r];
    }
  }
}

// ====== Layer-0 exp-scores, SLOT-PARALLEL (no loops) ==========================
__global__ void k_esx0(const int2* __restrict__ recA, const int* __restrict__ rcvA,
                       const float* __restrict__ s1, const float* __restrict__ s2,
                       const float* __restrict__ s3, float* __restrict__ esx) {
  const int j = blockIdx.x * 256 + threadIdx.x;
  if (j >= 2 * NEDGES) return;
  const int2 rec = recA[j];
  const int n = rcvA[j];
  const int o = rec.y & 0x3FFFFFFF;
  const int role = rec.y >> 30;
  const float4 A = ((const float4*)s1)[rec.x];
  const float4 T = ((const float4*)s2)[role ? o : n];
  const float4 D = ((const float4*)s3)[role ? n : o];
  float4 es;
  float s;
  s = A.x + T.x + D.x; s = s > 0.f ? s : 0.2f * s; es.x = __expf(s);
  s = A.y + T.y + D.y; s = s > 0.f ? s : 0.2f * s; es.y = __expf(s);
  s = A.z + T.z + D.z; s = s > 0.f ? s : 0.2f * s; es.z = __expf(s);
  s = A.w + T.w + D.w; s = s > 0.f ? s : 0.2f * s; es.w = __expf(s);
  ((float4*)esx)[j] = es;
}

// ====== Layer-0 denominator sums: per node, sequential esx reads ==============
__global__ void k_sums0n(const int* __restrict__ offs, const float* __restrict__ esx,
                         float* __restrict__ sums) {
  const int n = blockIdx.x * 256 + threadIdx.x;
  if (n >= NNODES) return;
  const int beg = offs[n], end = offs[n + 1];
  float4 acc = make_float4(0.f, 0.f, 0.f, 0.f);
  for (int j = beg; j < end; ++j) {
    const float4 v = ((const float4*)esx)[j];
    acc.x += v.x; acc.y += v.y; acc.z += v.z; acc.w += v.w;
  }
  ((float4*)sums)[n] = acc;
}

// ====== Layer-0 aggregate, wave/node, FUSED norm, FP8, depth-2 batched ========
// 16 lanes per slot (uint4 = 16B/lane = 256B row), 4 slots per stage, TWO
// stages' gather clusters issued before either is consumed (2 chains/wave in
// flight). Epilogue spread over all 64 lanes: lane (g,li) -> feature li*4+g.
__global__ __launch_bounds__(256) void k_agg0w(
    const int* __restrict__ offs, const int2* __restrict__ recA,
    const float* __restrict__ esx, const float* __restrict__ sums,
    const unsigned char* __restrict__ proj0f8, const float* __restrict__ x,
    const float* __restrict__ b0, __hip_bfloat16* __restrict__ out0b) {
  const int lane = threadIdx.x & 63, wid = threadIdx.x >> 6;
  const int n = blockIdx.x * 4 + wid;
  if (n >= NNODES) return;
  const int beg = offs[n], end = offs[n + 1];
  const int g = lane >> 4;   // slot group 0..3
  const int li = lane & 15;  // 16B chunk: row bytes li*16 .. li*16+15
  const float4 sn = ((const float4*)sums)[n];
  // acc: word w (feature li*4+w), component = head 0..3
  f32x4 a0 = (f32x4){0.f, 0.f, 0.f, 0.f};
  f32x4 a1 = (f32x4){0.f, 0.f, 0.f, 0.f};
  f32x4 a2 = (f32x4){0.f, 0.f, 0.f, 0.f};
  f32x4 a3 = (f32x4){0.f, 0.f, 0.f, 0.f};

// NOTE: stage prefix is rc##S (NOT rec##S) to avoid shadowing param recA.
#define GATHER(S, JS)                                                          \
  const int2 rc##S = recA[JS];                                                 \
  const float4 e##S = ((const float4*)esx)[JS];                                \
  const int o##S = rc##S.y & 0x3FFFFFFF;                                       \
  const float4 so##S = ((const float4*)sums)[o##S];                            \
  const uint4 r##S =                                                           \
      *(const uint4*)(proj0f8 + (size_t)rc##S.x * 256 + li * 16);

#define APPLY(S, LM)                                                           \
  {                                                                            \
    const float t0 =                                                           \
        (LM) * e##S.x * __builtin_amdgcn_rcpf(sn.x + so##S.x + 1e-16f);        \
    const float t1 =                                                           \
        (LM) * e##S.y * __builtin_amdgcn_rcpf(sn.y + so##S.y + 1e-16f);        \
    const float t2 =                                                           \
        (LM) * e##S.z * __builtin_amdgcn_rcpf(sn.z + so##S.z + 1e-16f);        \
    const float t3 =                                                           \
        (LM) * e##S.w * __builtin_amdgcn_rcpf(sn.w + so##S.w + 1e-16f);        \
    f32x2 c;                                                                   \
    c = __builtin_amdgcn_cvt_pk_f32_fp8(r##S.x, false);                        \
    a0[0] = fmaf(c[0], t0, a0[0]); a0[1] = fmaf(c[1], t1, a0[1]);              \
    c = __builtin_amdgcn_cvt_pk_f32_fp8(r##S.x, true);                         \
    a0[2] = fmaf(c[0], t2, a0[2]); a0[3] = fmaf(c[1], t3, a0[3]);              \
    c = __builtin_amdgcn_cvt_pk_f32_fp8(r##S.y, false);                        \
    a1[0] = fmaf(c[0], t0, a1[0]); a1[1] = fmaf(c[1], t1, a1[1]);              \
    c = __builtin_amdgcn_cvt_pk_f32_fp8(r##S.y, true);                         \
    a1[2] = fmaf(c[0], t2, a1[2]); a1[3] = fmaf(c[1], t3, a1[3]);              \
    c = __builtin_amdgcn_cvt_pk_f32_fp8(r##S.z, false);                        \
    a2[0] = fmaf(c[0], t0, a2[0]); a2[1] = fmaf(c[1], t1, a2[1]);              \
    c = __builtin_amdgcn_cvt_pk_f32_fp8(r##S.z, true);                         \
    a2[2] = fmaf(c[0], t2, a2[2]); a2[3] = fmaf(c[1], t3, a2[3]);              \
    c = __builtin_amdgcn_cvt_pk_f32_fp8(r##S.w, false);                        \
    a3[0] = fmaf(c[0], t0, a3[0]); a3[1] = fmaf(c[1], t1, a3[1]);              \
    c = __builtin_amdgcn_cvt_pk_f32_fp8(r##S.w, true);                         \
    a3[2] = fmaf(c[0], t2, a3[2]); a3[3] = fmaf(c[1], t3, a3[3]);              \
  }

  int j = beg;
  for (; j + 8 <= end; j += 8) {
    // both stages' gather clusters issued before either consume
    GATHER(A, j + g)
    GATHER(B, j + 4 + g)
    APPLY(A, 1.f)
    APPLY(B, 1.f)
  }
  for (; j < end; j += 4) {
    const bool lv = (j + g) < end;
    const int js = lv ? j + g : beg;
    GATHER(T, js)
    APPLY(T, lv ? 1.f : 0.f)
  }
#undef GATHER
#undef APPLY

  // combine the four slot-groups (all lanes end with full a0..a3)
#define RED(m)                                                                 \
  a0[0] += __shfl_xor(a0[0], m); a0[1] += __shfl_xor(a0[1], m);                \
  a0[2] += __shfl_xor(a0[2], m); a0[3] += __shfl_xor(a0[3], m);                \
  a1[0] += __shfl_xor(a1[0], m); a1[1] += __shfl_xor(a1[1], m);                \
  a1[2] += __shfl_xor(a1[2], m); a1[3] += __shfl_xor(a1[3], m);                \
  a2[0] += __shfl_xor(a2[0], m); a2[1] += __shfl_xor(a2[1], m);                \
  a2[2] += __shfl_xor(a2[2], m); a2[3] += __shfl_xor(a2[3], m);                \
  a3[0] += __shfl_xor(a3[0], m); a3[1] += __shfl_xor(a3[1], m);                \
  a3[2] += __shfl_xor(a3[2], m); a3[3] += __shfl_xor(a3[3], m);
  RED(16) RED(32)
#undef RED

  // epilogue on ALL 64 lanes: lane (g,li) -> feature f = li*4 + g
  const f32x4 aw = (g == 0) ? a0 : (g == 1) ? a1 : (g == 2) ? a2 : a3;
  const int f = li * 4 + g;
  const float xf = x[(size_t)n * 64 + f];
  const float e0 = aw[0] + xf + b0[f];
  const float e1 = aw[1] + xf + b0[64 + f];
  const float e2 = aw[2] + xf + b0[128 + f];
  const float e3 = aw[3] + xf + b0[192 + f];
#define EL(v_) ((v_) > 0.f ? (v_) : (__expf(v_) - 1.f))
  const float w0 = EL(e0);
  const float w1 = EL(e1);
  const float w2 = EL(e2);
  const float w3 = EL(e3);
#undef EL
  uint2 o;
  o.x = (unsigned)f2b(w0) | ((unsigned)f2b(w1) << 16);
  o.y = (unsigned)f2b(w2) | ((unsigned)f2b(w3) << 16);
  *(uint2*)(out0b + (size_t)n * 256 + f * 4) = o;
}

// ====== Layer-1 MFMA GEMM: [N,256] x [256,144] (k-permuted B) =================
#define LDA1 264
__global__ __launch_bounds__(256) void k_mm1(
    const __hip_bfloat16* __restrict__ hsrc, const short* __restrict__ B1,
    const float* __restrict__ b1, __hip_bfloat16* __restrict__ proj1,
    float* __restrict__ out, float* __restrict__ s1, float* __restrict__ s2,
    float* __restrict__ s3) {
  __shared__ short As[64 * LDA1];
  const int t = threadIdx.x;
  const int lane = t & 63, w = t >> 6;
  const int base = blockIdx.x * 64;
  for (int q = 0; q < 8; ++q) {
    const int i = q * 256 + t;
    const int r = i >> 5;
    const int c = (i & 31) * 8;
    int rg = base + r;
    if (rg >= NNODES) rg = NNODES - 1;
    const float4 v = *(const float4*)((const short*)hsrc + (size_t)rg * 256 + c);
    *(float4*)(&As[r * LDA1 + c]) = v;
  }
  __syncthreads();
  const short8* B8 = (const short8*)B1;
  f32x4 acc[9];
#pragma unroll
  for (int g = 0; g < 9; ++g) acc[g] = (f32x4){0.f, 0.f, 0.f, 0.f};
  const int aoff = (w * 16 + (lane & 15)) * LDA1 + (lane >> 4) * 8;
#pragma unroll
  for (int s = 0; s < 8; ++s) {
    const short8 af = *(const short8*)(&As[aoff + s * 32]);
#pragma unroll
    for (int g = 0; g < 9; ++g) {
      const short8 bf = B8[(g * 8 + s) * 64 + lane];
      acc[g] = __builtin_amdgcn_mfma_f32_16x16x32_bf16(af, bf, acc[g], 0, 0, 0);
    }
  }
  const int r0 = base + w * 16 + (lane >> 4) * 4;
  const int cn = lane & 15;
#pragma unroll
  for (int g = 0; g < 4; ++g) {
    const int col = g * 16 + cn;
#pragma unroll
    for (int r = 0; r < 4; ++r) {
      const int row = r0 + r;
      if (row < NNODES)
        proj1[(size_t)row * 64 + col] = __float2bfloat16(acc[g][r]);
    }
  }
#pragma unroll
  for (int g = 4; g < 8; ++g) {
    const int col = (g - 4) * 16 + cn;
    const float bv = b1[col];
#pragma unroll
    for (int r = 0; r < 4; ++r) {
      const int row = r0 + r;
      if (row < NNODES) out[(size_t)row * 64 + col] = acc[g][r] + bv;
    }
  }
#pragma unroll
  for (int r = 0; r < 4; ++r) {
    const int row = r0 + r;
    if (row < NNODES) {
      if (cn == 0) s1[row] = acc[8][r];
      else if (cn == 1) s2[row] = acc[8][r];
      else if (cn == 2) s3[row] = acc[8][r];
    }
  }
}

// ====== Layer-1 exp-scores, SLOT-PARALLEL =====================================
__global__ void k_esx1(const int2* __restrict__ recA, const int* __restrict__ rcvA,
                       const float* __restrict__ s1, const float* __restrict__ s2,
                       const float* __restrict__ s3, float* __restrict__ es1) {
  const int j = blockIdx.x * 256 + threadIdx.x;
  if (j >= 2 * NEDGES) return;
  const int2 rec = recA[j];
  const int n = rcvA[j];
  const int o = rec.y & 0x3FFFFFFF;
  const int role = rec.y >> 30;
  float s = s1[rec.x] + s2[role ? o : n] + s3[role ? n : o];
  s = s > 0.f ? s : 0.2f * s;
  es1[j] = __expf(s);
}

// ====== Layer-1 denominator sums: per node, sequential ========================
__global__ void k_sums1n(const int* __restrict__ offs, const float* __restrict__ es1,
                         float* __restrict__ sums) {
  const int n = blockIdx.x * 256 + threadIdx.x;
  if (n >= NNODES) return;
  const int beg = offs[n], end = offs[n + 1];
  float acc = 0.f;
  for (int j = beg; j < end; ++j) acc += es1[j];
  sums[n] = acc;
}

// ========== Layer-1 aggregate, wave/node, FUSED normalization =================
// 8 lanes per slot (uint4 = 16B/lane), 8 slots per wave-step; group-combine via
// __shfl_xor butterfly (8,16,32).
__global__ __launch_bounds__(256) void k_agg1(
    const int* __restrict__ offs, const int2* __restrict__ recA,
    const float* __restrict__ es1, const float* __restrict__ sums,
    const __hip_bfloat16* __restrict__ proj1, float* __restrict__ dout) {
  const int lane = threadIdx.x & 63, wid = threadIdx.x >> 6;
  const int n = blockIdx.x * 4 + wid;
  if (n >= NNODES) return;
  const int beg = offs[n], end = offs[n + 1];
  if (beg == end) return;  // dout row already holds skip+bias from k_mm1
  const int g = lane >> 3;  // slot group 0..7
  const int li = lane & 7;  // features li*8 .. li*8+7
  const float sn = sums[n];
  float a0 = 0.f, a1 = 0.f, a2 = 0.f, a3 = 0.f;
  float a4 = 0.f, a5 = 0.f, a6 = 0.f, a7 = 0.f;

#define SLOT(J, LIVE)                                                          \
  {                                                                            \
    const int jj = (J) + g;                                                    \
    const bool lv = (LIVE);                                                    \
    const int js = lv ? jj : beg;                                              \
    const int2 rec = recA[js];                                                 \
    const int o = rec.y & 0x3FFFFFFF;                                          \
    const float e = es1[js];                                                   \
    const float t =                                                            \
        (lv ? e : 0.f) * __builtin_amdgcn_rcpf(sn + sums[o] + 1e-16f);         \
    const uint4 r = *(const uint4*)(proj1 + (size_t)rec.x * 64 + li * 8);      \
    a0 = fmaf(bits2f_lo(r.x), t, a0);                                          \
    a1 = fmaf(bits2f_hi(r.x), t, a1);                                          \
    a2 = fmaf(bits2f_lo(r.y), t, a2);                                          \
    a3 = fmaf(bits2f_hi(r.y), t, a3);                                          \
    a4 = fmaf(bits2f_lo(r.z), t, a4);                                          \
    a5 = fmaf(bits2f_hi(r.z), t, a5);                                          \
    a6 = fmaf(bits2f_lo(r.w), t, a6);                                          \
    a7 = fmaf(bits2f_hi(r.w), t, a7);                                          \
  }

  int j = beg;
  for (; j + 8 <= end; j += 8) SLOT(j, true)
  for (; j < end; j += 8) SLOT(j, jj < end)
#undef SLOT

  // butterfly-reduce across the 8 slot groups
#define RED(m)                                                                 \
  a0 += __shfl_xor(a0, m); a1 += __shfl_xor(a1, m);                            \
  a2 += __shfl_xor(a2, m); a3 += __shfl_xor(a3, m);                            \
  a4 += __shfl_xor(a4, m); a5 += __shfl_xor(a5, m);                            \
  a6 += __shfl_xor(a6, m); a7 += __shfl_xor(a7, m);
  RED(8) RED(16) RED(32)
#undef RED

  if (g == 0) {
    float4* dp = (float4*)(dout + (size_t)n * 64 + li * 8);
    float4 d0 = dp[0], d1 = dp[1];
    d0.x += a0; d0.y += a1; d0.z += a2; d0.w += a3;
    d1.x += a4; d1.y += a5; d1.z += a6; d1.w += a7;
    dp[0] = d0;
    dp[1] = d1;
  }
}

extern "C" void kernel_launch(void* const* d_in, const int* in_sizes, int n_in,
                              void* d_out, int out_size, void* d_ws, size_t ws_size,
                              hipStream_t stream) {
  const float* x = (const float*)d_in[0];
  const int* ei = (const int*)d_in[1];
  const float* W0 = (const float*)d_in[2];
  const float* a10 = (const float*)d_in[3];
  const float* a20 = (const float*)d_in[4];
  const float* a30 = (const float*)d_in[5];
  // d_in[6] = Wskip0: unused (layer-0 skip is identity, F==DIN)
  const float* b0 = (const float*)d_in[7];
  const float* W1 = (const float*)d_in[8];
  const float* a11 = (const float*)d_in[9];
  const float* a21 = (const float*)d_in[10];
  const float* a31 = (const float*)d_in[11];
  const float* Wskip1 = (const float*)d_in[12];
  const float* b1 = (const float*)d_in[13];
  float* out = (float*)d_out;

  // ---- Workspace layout (region sizes unchanged from R10) ----
  unsigned char* proj0f8 = (unsigned char*)d_ws;       // N*256 B (fp8 head-ilv)
  __hip_bfloat16* out0b =
      (__hip_bfloat16*)d_ws + (size_t)NNODES * 256;    // N*256 bf16 (head-ilv)
  float* s1_0 = (float*)(out0b + (size_t)NNODES * 256);  // N*4 x3
  float* s2_0 = s1_0 + (size_t)NNODES * 4;
  float* s3_0 = s2_0 + (size_t)NNODES * 4;
  float* sums0 = s3_0 + (size_t)NNODES * 4;            // N*4
  float* esx0 = sums0 + (size_t)NNODES * 4;            // 2E*4
  int2* recA = (int2*)(esx0 + (size_t)2 * NEDGES * 4); // 2E int2
  int* rcvA = (int*)(recA + 2 * NEDGES);               // 2E
  int* offs = rcvA + 2 * NEDGES;                       // N+16
  float* s1_1 = (float*)(offs + NNODES + 16);          // N x3
  float* s2_1 = s1_1 + NNODES;
  float* s3_1 = s2_1 + NNODES;
  float* sums1 = s3_1 + NNODES;                        // N
  __hip_bfloat16* B0swz = (__hip_bfloat16*)(sums1 + NNODES);  // 17408 bf16
  __hip_bfloat16* B1swz = B0swz + 17408;               // 36864 bf16
  // CSR-build int scratch aliases esx0 (dead until k_esx0):
  int* deg = (int*)esx0;
  int* cursor = deg + NNODES;
  int* bsums = cursor + NNODES;

  __hip_bfloat16* proj1 = (__hip_bfloat16*)d_ws;  // reuse proj0 region (bf16)
  float* es1 = esx0;              // layer-1 exp/att slots (esx0 dead after agg0w)

  // ---- fused weight prep ----
  k_prep<<<212, 256, 0, stream>>>(W0, a10, a20, a30, W1, Wskip1, a11, a21, a31,
                                  B0swz, B1swz);

  // ---- Layer-0 projection + scores via MFMA (fp8 proj0) ----
  k_mm0<<<(NNODES + 63) / 64, 256, 0, stream>>>(x, (const short*)B0swz, proj0f8,
                                                s1_0, s2_0, s3_0);

  // ---- CSR build ----
  hipMemsetAsync(deg, 0, NNODES * sizeof(int), stream);
  k_deg<<<(2 * NEDGES + 255) / 256, 256, 0, stream>>>(ei, deg);
  k_scan1<<<NB_SCAN, 256, 0, stream>>>(deg, offs, bsums);
  k_scan2<<<1, 512, 0, stream>>>(bsums);
  k_scan3<<<NB_SCAN, 256, 0, stream>>>(offs, bsums, cursor);
  k_fill3<<<(2 * NEDGES + 255) / 256, 256, 0, stream>>>(ei, cursor, recA, rcvA);

  // ---- Layer 0: slot exp -> node sums -> fused(att+aggregate, fp8) ----
  const int NBS = (2 * NEDGES + 255) / 256;
  k_esx0<<<NBS, 256, 0, stream>>>(recA, rcvA, s1_0, s2_0, s3_0, esx0);
  k_sums0n<<<NB_SCAN, 256, 0, stream>>>(offs, esx0, sums0);
  k_agg0w<<<(NNODES + 3) / 4, 256, 0, stream>>>(offs, recA, esx0, sums0,
                                                proj0f8, x, b0, out0b);

  // ---- Layer 1: MFMA GEMM -> slot exp -> sums -> fused(att+aggregate) ----
  k_mm1<<<(NNODES + 63) / 64, 256, 0, stream>>>(out0b, (const short*)B1swz, b1,
                                                proj1, out, s1_1, s2_1, s3_1);
  k_esx1<<<NBS, 256, 0, stream>>>(recA, rcvA, s1_1, s2_1, s3_1, es1);
  k_sums1n<<<NB_SCAN, 256, 0, stream>>>(offs, es1, sums1);
  k_agg1<<<(NNODES + 3) / 4, 256, 0, stream>>>(offs, recA, es1, sums1, proj1,
                                               out);
}